// Round 1
// baseline (18751.616 us; speedup 1.0000x reference)
//
#include <hip/hip_runtime.h>

typedef _Float16 half_t;
typedef _Float16 half8 __attribute__((ext_vector_type(8)));
typedef float floatx4 __attribute__((ext_vector_type(4)));

#define NT   300
#define NB   256
#define DIN  512
#define DH   512
#define DOUT 128
#define DX   384        // IN - OUT (x part of stage-1 input)
#define K_L  1024       // LSTM layer GEMM K  ([z | h_prev])
#define NG   2048       // 4*DH gate rows

// ---------------------------------------------------------------------------
// pre-pass kernels (run every call — no static caching allowed)
// ---------------------------------------------------------------------------

__global__ void cvt_f32_f16(const float* __restrict__ src, half_t* __restrict__ dst, int n) {
    for (int i = blockIdx.x * blockDim.x + threadIdx.x; i < n; i += gridDim.x * blockDim.x)
        dst[i] = (half_t)src[i];
}

// Pack [w_ih | w_hh] into [2048][1024] fp16 with gate-interleaved rows:
//   n' = G(d,g) = (d>>4)*64 + g*16 + (d&15)
// so a 64-wide col tile holds all 4 gates of 16 dims, gate = col-fragment idx,
// dim-low = lane&15. Also fold b_ih+b_hh into one permuted f32 bias.
__global__ void pack_layer(const float* __restrict__ wih, const float* __restrict__ whh,
                           const float* __restrict__ bih, const float* __restrict__ bhh,
                           half_t* __restrict__ Wp, float* __restrict__ biasP) {
    const int total = NG * K_L;
    for (int i = blockIdx.x * blockDim.x + threadIdx.x; i < total; i += gridDim.x * blockDim.x) {
        int np = i >> 10;
        int k  = i & 1023;
        int d  = ((np >> 6) << 4) | (np & 15);
        int g  = (np >> 4) & 3;
        int srow = g * DH + d;
        float v = (k < DH) ? wih[srow * DH + k] : whh[srow * DH + (k - DH)];
        Wp[i] = (half_t)v;
        if (k == 0) biasP[np] = bih[srow] + bhh[srow];
    }
}

// Zero c0/c1 and the h-prev halves of parity-0 act buffers; seed ybuf with
// prev0 = x[0, :, -OUT:]  (PRED_WEIGHT==1 -> fb == prev exactly).
__global__ void init_state(const float* __restrict__ x, float* __restrict__ c0, float* __restrict__ c1,
                           half_t* __restrict__ act0, half_t* __restrict__ act1, half_t* __restrict__ ybuf) {
    const int total = NB * DH;
    for (int i = blockIdx.x * blockDim.x + threadIdx.x; i < total; i += gridDim.x * blockDim.x) {
        int m = i >> 9, d = i & 511;
        c0[i] = 0.f;
        c1[i] = 0.f;
        act0[m * 1024 + 512 + d] = (half_t)0.f;
        act1[m * 1024 + 512 + d] = (half_t)0.f;
        if (d < DOUT) ybuf[m * DOUT + d] = (half_t)x[m * DIN + DX + d];
    }
}

// ---------------------------------------------------------------------------
// stage kernels: WG = 256 thr (4 waves), WG tile 64 rows x 128 cols,
// wave tile 32x64 (2 row-frags x 4 col-frags), K-chunk 32, LDS pad stride 40.
// MFMA 16x16x32 f16: A lane: row=l&15, k=(l>>4)*8+j ; B lane: col=l&15 ;
// D lane: col=l&15, row=(l>>4)*4+reg.
// ---------------------------------------------------------------------------

// z = relu([x_t(384) | y_prev(128)] @ W1^T + b1) -> fp16 into act0[p][:, 0:512]
__global__ __launch_bounds__(256) void z_kernel(
        const float* __restrict__ xt,     // [256][512] f32
        const half_t* __restrict__ ybuf,  // [256][128]
        const half_t* __restrict__ W1h,   // [512][512]
        const float* __restrict__ b1,
        half_t* __restrict__ zout)        // row stride 1024, cols 0..511
{
    __shared__ __align__(16) half_t As[64][40];
    __shared__ __align__(16) half_t Bs[128][40];
    const int tid = threadIdx.x;
    const int lane = tid & 63, wid = tid >> 6;
    const int wave_r = wid >> 1, wave_c = wid & 1;
    const int l15 = lane & 15, l4 = lane >> 4;
    const int row0 = blockIdx.x * 64, col0 = blockIdx.y * 128;
    const int ar = tid >> 2, ak = (tid & 3) * 8;

    floatx4 acc[2][4] = {};

    for (int kk = 0; kk < DIN; kk += 32) {
        if (kk < DX) {
            const float* s = xt + (size_t)(row0 + ar) * DIN + kk + ak;
            float4 f0 = *(const float4*)s;
            float4 f1 = *(const float4*)(s + 4);
            half8 h;
            h[0] = (half_t)f0.x; h[1] = (half_t)f0.y; h[2] = (half_t)f0.z; h[3] = (half_t)f0.w;
            h[4] = (half_t)f1.x; h[5] = (half_t)f1.y; h[6] = (half_t)f1.z; h[7] = (half_t)f1.w;
            *(half8*)&As[ar][ak] = h;
        } else {
            *(half8*)&As[ar][ak] = *(const half8*)&ybuf[(row0 + ar) * DOUT + (kk - DX) + ak];
        }
        *(half8*)&Bs[ar][ak]      = *(const half8*)&W1h[(col0 + ar) * DIN + kk + ak];
        *(half8*)&Bs[64 + ar][ak] = *(const half8*)&W1h[(col0 + 64 + ar) * DIN + kk + ak];
        __syncthreads();
        half8 af[2], bf[4];
        #pragma unroll
        for (int rf = 0; rf < 2; ++rf) af[rf] = *(const half8*)&As[wave_r * 32 + rf * 16 + l15][l4 * 8];
        #pragma unroll
        for (int cf = 0; cf < 4; ++cf) bf[cf] = *(const half8*)&Bs[wave_c * 64 + cf * 16 + l15][l4 * 8];
        #pragma unroll
        for (int rf = 0; rf < 2; ++rf)
            #pragma unroll
            for (int cf = 0; cf < 4; ++cf)
                acc[rf][cf] = __builtin_amdgcn_mfma_f32_16x16x32_f16(af[rf], bf[cf], acc[rf][cf], 0, 0, 0);
        __syncthreads();
    }
    #pragma unroll
    for (int rf = 0; rf < 2; ++rf) {
        #pragma unroll
        for (int cf = 0; cf < 4; ++cf) {
            int n = col0 + wave_c * 64 + cf * 16 + l15;
            float bb = b1[n];
            #pragma unroll
            for (int r = 0; r < 4; ++r) {
                int m = row0 + wave_r * 32 + rf * 16 + l4 * 4 + r;
                float v = acc[rf][cf][r] + bb;
                v = fmaxf(v, 0.f);
                zout[m * 1024 + n] = (half_t)v;
            }
        }
    }
}

// gates = A @ Wp^T + biasP ; fused LSTM cell update; h written fp16 to 1-2 dests
__global__ __launch_bounds__(256) void lstm_kernel(
        const half_t* __restrict__ A,     // [256][1024] = [z|h_prev] or [h0|h1_prev]
        const half_t* __restrict__ Wp,    // [2048][1024] gate-permuted
        const float* __restrict__ biasP,  // [2048] permuted
        float* __restrict__ cbuf,         // [256][512] f32 cell state
        half_t* __restrict__ hout1,       // row stride 1024, col base pre-applied
        half_t* __restrict__ hout2)       // may be nullptr
{
    __shared__ __align__(16) half_t As[64][40];
    __shared__ __align__(16) half_t Bs[128][40];
    const int tid = threadIdx.x;
    const int lane = tid & 63, wid = tid >> 6;
    const int wave_r = wid >> 1, wave_c = wid & 1;
    const int l15 = lane & 15, l4 = lane >> 4;
    const int row0 = blockIdx.x * 64, col0 = blockIdx.y * 128;
    const int ar = tid >> 2, ak = (tid & 3) * 8;

    floatx4 acc[2][4] = {};

    for (int kk = 0; kk < K_L; kk += 32) {
        *(half8*)&As[ar][ak]      = *(const half8*)&A[(row0 + ar) * 1024 + kk + ak];
        *(half8*)&Bs[ar][ak]      = *(const half8*)&Wp[(size_t)(col0 + ar) * K_L + kk + ak];
        *(half8*)&Bs[64 + ar][ak] = *(const half8*)&Wp[(size_t)(col0 + 64 + ar) * K_L + kk + ak];
        __syncthreads();
        half8 af[2], bf[4];
        #pragma unroll
        for (int rf = 0; rf < 2; ++rf) af[rf] = *(const half8*)&As[wave_r * 32 + rf * 16 + l15][l4 * 8];
        #pragma unroll
        for (int cf = 0; cf < 4; ++cf) bf[cf] = *(const half8*)&Bs[wave_c * 64 + cf * 16 + l15][l4 * 8];
        #pragma unroll
        for (int rf = 0; rf < 2; ++rf)
            #pragma unroll
            for (int cf = 0; cf < 4; ++cf)
                acc[rf][cf] = __builtin_amdgcn_mfma_f32_16x16x32_f16(af[rf], bf[cf], acc[rf][cf], 0, 0, 0);
        __syncthreads();
    }

    // epilogue: wave's 64-col group q holds gates 0..3 (col frag) of dims d=q*16+l15
    const int q = blockIdx.y * 2 + wave_c;
    const int d = q * 16 + l15;
    const float bi = biasP[q * 64 + l15];
    const float bfv = biasP[q * 64 + 16 + l15];
    const float bg = biasP[q * 64 + 32 + l15];
    const float bo = biasP[q * 64 + 48 + l15];
    #pragma unroll
    for (int rf = 0; rf < 2; ++rf) {
        #pragma unroll
        for (int r = 0; r < 4; ++r) {
            int m = row0 + wave_r * 32 + rf * 16 + l4 * 4 + r;
            float gi = acc[rf][0][r] + bi;
            float gf = acc[rf][1][r] + bfv;
            float gg = acc[rf][2][r] + bg;
            float go = acc[rf][3][r] + bo;
            float si = 1.f / (1.f + expf(-gi));
            float sf = 1.f / (1.f + expf(-gf));
            float so = 1.f / (1.f + expf(-go));
            float cn = sf * cbuf[m * DH + d] + si * tanhf(gg);
            float hn = so * tanhf(cn);
            cbuf[m * DH + d] = cn;
            hout1[m * 1024 + d] = (half_t)hn;
            if (hout2) hout2[m * 1024 + d] = (half_t)hn;
        }
    }
}

// y = h1 @ W2^T + b2 -> f32 to d_out[t], fp16 to ybuf (feedback)
__global__ __launch_bounds__(256) void y_kernel(
        const half_t* __restrict__ A,    // h1: row stride 1024 (base pre-offset +512)
        const half_t* __restrict__ W2h,  // [128][512]
        const float* __restrict__ b2,
        float* __restrict__ yout,        // [256][128]
        half_t* __restrict__ ybuf)       // [256][128]
{
    __shared__ __align__(16) half_t As[64][40];
    __shared__ __align__(16) half_t Bs[128][40];
    const int tid = threadIdx.x;
    const int lane = tid & 63, wid = tid >> 6;
    const int wave_r = wid >> 1, wave_c = wid & 1;
    const int l15 = lane & 15, l4 = lane >> 4;
    const int row0 = blockIdx.x * 64;
    const int ar = tid >> 2, ak = (tid & 3) * 8;

    floatx4 acc[2][4] = {};

    for (int kk = 0; kk < DH; kk += 32) {
        *(half8*)&As[ar][ak]      = *(const half8*)&A[(row0 + ar) * 1024 + kk + ak];
        *(half8*)&Bs[ar][ak]      = *(const half8*)&W2h[ar * DH + kk + ak];
        *(half8*)&Bs[64 + ar][ak] = *(const half8*)&W2h[(64 + ar) * DH + kk + ak];
        __syncthreads();
        half8 af[2], bf[4];
        #pragma unroll
        for (int rf = 0; rf < 2; ++rf) af[rf] = *(const half8*)&As[wave_r * 32 + rf * 16 + l15][l4 * 8];
        #pragma unroll
        for (int cf = 0; cf < 4; ++cf) bf[cf] = *(const half8*)&Bs[wave_c * 64 + cf * 16 + l15][l4 * 8];
        #pragma unroll
        for (int rf = 0; rf < 2; ++rf)
            #pragma unroll
            for (int cf = 0; cf < 4; ++cf)
                acc[rf][cf] = __builtin_amdgcn_mfma_f32_16x16x32_f16(af[rf], bf[cf], acc[rf][cf], 0, 0, 0);
        __syncthreads();
    }
    #pragma unroll
    for (int rf = 0; rf < 2; ++rf) {
        #pragma unroll
        for (int cf = 0; cf < 4; ++cf) {
            int n = wave_c * 64 + cf * 16 + l15;   // 0..127
            float bb = b2[n];
            #pragma unroll
            for (int r = 0; r < 4; ++r) {
                int m = row0 + wave_r * 32 + rf * 16 + l4 * 4 + r;
                float v = acc[rf][cf][r] + bb;
                yout[m * DOUT + n] = v;
                ybuf[m * DOUT + n] = (half_t)v;
            }
        }
    }
}

// ---------------------------------------------------------------------------

extern "C" void kernel_launch(void* const* d_in, const int* in_sizes, int n_in,
                              void* d_out, int out_size, void* d_ws, size_t ws_size,
                              hipStream_t stream) {
    const float* x    = (const float*)d_in[0];
    const float* w1   = (const float*)d_in[1];
    const float* b1   = (const float*)d_in[2];
    const float* w_ih = (const float*)d_in[3];
    const float* w_hh = (const float*)d_in[4];
    const float* b_ih = (const float*)d_in[5];
    const float* b_hh = (const float*)d_in[6];
    const float* w2   = (const float*)d_in[7];
    const float* b2   = (const float*)d_in[8];
    float* out = (float*)d_out;

    char* ws = (char*)d_ws;
    size_t off = 0;
    auto take = [&](size_t bytes) -> char* {
        char* p = ws + off;
        off += (bytes + 255) & ~(size_t)255;
        return p;
    };
    half_t* W1h   = (half_t*)take((size_t)512 * 512 * 2);
    half_t* W2h   = (half_t*)take((size_t)128 * 512 * 2);
    half_t* Wl0   = (half_t*)take((size_t)NG * K_L * 2);
    half_t* Wl1   = (half_t*)take((size_t)NG * K_L * 2);
    float*  biasP0 = (float*)take((size_t)NG * 4);
    float*  biasP1 = (float*)take((size_t)NG * 4);
    float*  c0    = (float*)take((size_t)NB * DH * 4);
    float*  c1    = (float*)take((size_t)NB * DH * 4);
    half_t* act0  = (half_t*)take((size_t)2 * NB * 1024 * 2);  // parity-double [z|h0prev]
    half_t* act1  = (half_t*)take((size_t)2 * NB * 1024 * 2);  // parity-double [h0|h1prev]
    half_t* ybuf  = (half_t*)take((size_t)NB * DOUT * 2);
    (void)in_sizes; (void)n_in; (void)out_size; (void)ws_size;

    cvt_f32_f16<<<256, 256, 0, stream>>>(w1, W1h, 512 * 512);
    cvt_f32_f16<<<64, 256, 0, stream>>>(w2, W2h, 128 * 512);
    pack_layer<<<1024, 256, 0, stream>>>(w_ih, w_hh, b_ih, b_hh, Wl0, biasP0);
    pack_layer<<<1024, 256, 0, stream>>>(w_ih + (size_t)NG * DH, w_hh + (size_t)NG * DH,
                                         b_ih + NG, b_hh + NG, Wl1, biasP1);
    init_state<<<128, 256, 0, stream>>>(x, c0, c1, act0, act1, ybuf);

    for (int t = 0; t < NT; ++t) {
        const int p = t & 1, pn = p ^ 1;
        half_t* a0r = act0 + (size_t)p  * NB * 1024;
        half_t* a0w = act0 + (size_t)pn * NB * 1024;
        half_t* a1r = act1 + (size_t)p  * NB * 1024;
        half_t* a1w = act1 + (size_t)pn * NB * 1024;

        // z(t) -> act0[p][:, 0:512]
        z_kernel<<<dim3(4, 4), 256, 0, stream>>>(x + (size_t)t * NB * DIN, ybuf, W1h, b1, a0r);
        // layer0: reads act0[p] = [z | h0(t-1)]; h0(t) -> act1[p][:,0:512] and act0[pn][:,512:]
        lstm_kernel<<<dim3(4, 16), 256, 0, stream>>>(a0r, Wl0, biasP0, c0, a1r, a0w + 512);
        // layer1: reads act1[p] = [h0(t) | h1(t-1)]; h1(t) -> act1[pn][:,512:]
        lstm_kernel<<<dim3(4, 16), 256, 0, stream>>>(a1r, Wl1, biasP1, c1, a1w + 512, (half_t*)nullptr);
        // y(t) from h1(t); writes d_out[t] (f32) and ybuf (fp16 feedback)
        y_kernel<<<dim3(4, 1), 256, 0, stream>>>(a1w + 512, W2h, b2, out + (size_t)t * NB * DOUT, ybuf);
    }
}

// Round 2
// 18659.412 us; speedup vs baseline: 1.0049x; 1.0049x over previous
//
#include <hip/hip_runtime.h>

typedef _Float16 half_t;
typedef _Float16 half8 __attribute__((ext_vector_type(8)));
typedef float floatx4 __attribute__((ext_vector_type(4)));

#define NT   300
#define NB   256
#define DIN  512
#define DH   512
#define DOUT 128
#define DX   384        // IN - OUT
#define KZ   896        // folded z GEMM K: 384 (x) + 512 (h1)
#define NG   2048       // 4*DH gate rows
#define NWG  256
#define SMEM 131072     // 128KB stationary B slice

// ---------------------------------------------------------------------------
// helpers
// ---------------------------------------------------------------------------

__device__ __forceinline__ float sigm(float x)  { return __builtin_amdgcn_rcpf(1.f + __expf(-x)); }
__device__ __forceinline__ float tanhx(float x) { return 1.f - 2.f * __builtin_amdgcn_rcpf(__expf(2.f * x) + 1.f); }

__device__ __forceinline__ half8 cvt8(const float* s) {
    float4 f0 = *(const float4*)s, f1 = *(const float4*)(s + 4);
    half8 h;
    h[0] = (half_t)f0.x; h[1] = (half_t)f0.y; h[2] = (half_t)f0.z; h[3] = (half_t)f0.w;
    h[4] = (half_t)f1.x; h[5] = (half_t)f1.y; h[6] = (half_t)f1.z; h[7] = (half_t)f1.w;
    return h;
}

// grid barrier: monotonic counter, agent scope (cross-XCD safe).
__device__ __forceinline__ void grid_barrier(unsigned* cnt, unsigned target) {
    __syncthreads();                       // all waves drain their stores (vmcnt 0) to L2
    if (threadIdx.x == 0) {
        __hip_atomic_fetch_add(cnt, 1u, __ATOMIC_RELEASE, __HIP_MEMORY_SCOPE_AGENT);  // wb L2
        while (__hip_atomic_load(cnt, __ATOMIC_RELAXED, __HIP_MEMORY_SCOPE_AGENT) < target)
            __builtin_amdgcn_s_sleep(1);
        __builtin_amdgcn_fence(__ATOMIC_ACQUIRE, "agent");                            // inv L1/L2
    }
    __syncthreads();
}

// ---------------------------------------------------------------------------
// pre-pass kernels (every call — no caching allowed)
// ---------------------------------------------------------------------------

__global__ void cvt_f32_f16(const float* __restrict__ src, half_t* __restrict__ dst, int n) {
    for (int i = blockIdx.x * blockDim.x + threadIdx.x; i < n; i += gridDim.x * blockDim.x)
        dst[i] = (half_t)src[i];
}

// W1f = [W1x | W1y@W2] (512 x 896) fp16 ; b1f = b1 + W1y@b2
__global__ void fold_w1(const float* __restrict__ w1, const float* __restrict__ w2,
                        const float* __restrict__ b1, const float* __restrict__ b2,
                        half_t* __restrict__ W1f, float* __restrict__ b1f) {
    __shared__ float wy[128], b2s[128];
    const int h = blockIdx.x, tid = threadIdx.x;
    if (tid < 128) { wy[tid] = w1[(size_t)h * DIN + DX + tid]; b2s[tid] = b2[tid]; }
    __syncthreads();
    for (int k = tid; k < DX; k += 256) W1f[(size_t)h * KZ + k] = (half_t)w1[(size_t)h * DIN + k];
    for (int d = tid; d < DH; d += 256) {
        float s = 0.f;
        for (int j = 0; j < 128; ++j) s += wy[j] * w2[(size_t)j * DH + d];
        W1f[(size_t)h * KZ + DX + d] = (half_t)s;
    }
    if (tid == 0) {
        float s = 0.f;
        for (int j = 0; j < 128; ++j) s += wy[j] * b2s[j];
        b1f[h] = b1[h] + s;
    }
}

// Pack [w_ih | w_hh] frag-major with gate interleave.
// packed col n = (d>>4)*64 + g*16 + (d&15); layout unit u = ((ct*32+kf)*4+cf)*64+lane,
// holding half8 of B[k = kf*32+(lane>>4)*8 + j][n = ct*64+cf*16+(lane&15)].
__global__ void pack_lstm(const float* __restrict__ wih, const float* __restrict__ whh,
                          const float* __restrict__ bih, const float* __restrict__ bhh,
                          half_t* __restrict__ Wp, float* __restrict__ biasP) {
    const int u = blockIdx.x * blockDim.x + threadIdx.x;   // 0..262143
    const int lane = u & 63, cf = (u >> 6) & 3, kf = (u >> 8) & 31, ct = u >> 13;
    const int n = ct * 64 + cf * 16 + (lane & 15);
    const int d = ((n >> 6) << 4) | (n & 15);
    const int g = (n >> 4) & 3;
    const int srow = g * DH + d;
    const int k0 = kf * 32 + (lane >> 4) * 8;
    const float* src = (k0 < DH) ? (wih + (size_t)srow * DH + k0)
                                 : (whh + (size_t)srow * DH + (k0 - DH));
    half8 v;
    #pragma unroll
    for (int j = 0; j < 8; ++j) v[j] = (half_t)src[j];
    *(half8*)&Wp[(size_t)u * 8] = v;
    if (kf == 0 && (lane >> 4) == 0) biasP[n] = bih[srow] + bhh[srow];
}

__global__ void init_all(half_t* act0, half_t* act1, float* c0, float* c1, unsigned* cnt) {
    const int step = gridDim.x * blockDim.x;
    const int i0 = blockIdx.x * blockDim.x + threadIdx.x;
    for (int k = i0; k < 2 * NB * 1024; k += step) { act0[k] = (half_t)0.f; act1[k] = (half_t)0.f; }
    for (int k = i0; k < NB * DH; k += step) { c0[k] = 0.f; c1[k] = 0.f; }
    if (i0 == 0) *cnt = 0u;
}

// ---------------------------------------------------------------------------
// persistent cooperative kernel
// 256 WGs x 256 thr (1/CU). grp0 = WGs 0..127 (lstm0), grp1 = 128..255 (lstm1).
// Per step: S1 { z(t) on WGs 0..63 ; y(t-1) on WGs 128..135 } | S2 lstm0 | S3 lstm1.
// ---------------------------------------------------------------------------

__device__ __forceinline__ void lstm_body(const half_t* __restrict__ A, const half_t* __restrict__ Bst,
                                          const float* __restrict__ bP, float* __restrict__ cb,
                                          half_t* __restrict__ hd1, half_t* __restrict__ hd2,
                                          int ct, int rt, int lane, int wid) {
    const int l15 = lane & 15, l4 = lane >> 4;
    const int wrow = rt * 64 + wid * 16;
    floatx4 acc[4] = {};
    #pragma unroll 4
    for (int kf = 0; kf < 32; ++kf) {
        const int kk = kf * 32;
        half8 a = *(const half8*)&A[(size_t)(wrow + l15) * 1024 + kk + l4 * 8];
        #pragma unroll
        for (int cf = 0; cf < 4; ++cf) {
            half8 b = *(const half8*)&Bst[(size_t)((kf * 4 + cf) * 64 + lane) * 8];
            acc[cf] = __builtin_amdgcn_mfma_f32_16x16x32_f16(a, b, acc[cf], 0, 0, 0);
        }
    }
    const int d = ct * 16 + l15;
    const float bi = bP[ct * 64 + l15], bf_ = bP[ct * 64 + 16 + l15];
    const float bg = bP[ct * 64 + 32 + l15], bo = bP[ct * 64 + 48 + l15];
    #pragma unroll
    for (int r = 0; r < 4; ++r) {
        const int m = wrow + l4 * 4 + r;
        const float gi = acc[0][r] + bi, gf = acc[1][r] + bf_;
        const float gg = acc[2][r] + bg, go = acc[3][r] + bo;
        const float si = sigm(gi), sf = sigm(gf), so = sigm(go);
        const float cn = sf * cb[(size_t)m * DH + d] + si * tanhx(gg);
        const float hn = so * tanhx(cn);
        cb[(size_t)m * DH + d] = cn;
        hd1[(size_t)m * 1024 + d] = (half_t)hn;
        if (hd2) hd2[(size_t)m * 1024 + d] = (half_t)hn;
    }
}

__device__ __forceinline__ void y_body(const half_t* __restrict__ a1r, const half_t* __restrict__ W2h,
                                       const float* __restrict__ b2, float* __restrict__ yo,
                                       int lwg, int lane, int wid) {
    const int l15 = lane & 15, l4 = lane >> 4;
    const int row0 = lwg * 32;
    const int wr = wid >> 1, wc = wid & 1;
    const int arow = row0 + wr * 16 + l15;
    floatx4 acc[4] = {};
    #pragma unroll 2
    for (int kf = 0; kf < 16; ++kf) {
        const int kk = kf * 32;
        half8 a = *(const half8*)&a1r[(size_t)arow * 1024 + 512 + kk + l4 * 8];
        #pragma unroll
        for (int cf = 0; cf < 4; ++cf) {
            const int n = wc * 64 + cf * 16 + l15;
            half8 b = *(const half8*)&W2h[(size_t)n * DH + kk + l4 * 8];
            acc[cf] = __builtin_amdgcn_mfma_f32_16x16x32_f16(a, b, acc[cf], 0, 0, 0);
        }
    }
    #pragma unroll
    for (int cf = 0; cf < 4; ++cf) {
        const int n = wc * 64 + cf * 16 + l15;
        const float bb = b2[n];
        #pragma unroll
        for (int r = 0; r < 4; ++r) {
            const int m = row0 + wr * 16 + l4 * 4 + r;
            yo[(size_t)m * DOUT + n] = acc[cf][r] + bb;
        }
    }
}

__global__ void __launch_bounds__(256) rnn_persistent(
        const float* __restrict__ x, const half_t* __restrict__ W1h,
        const half_t* __restrict__ W1f, const float* __restrict__ b1,
        const float* __restrict__ b1f, const half_t* __restrict__ Wl0p,
        const float* __restrict__ bP0, const half_t* __restrict__ Wl1p,
        const float* __restrict__ bP1, const half_t* __restrict__ W2h,
        const float* __restrict__ b2, half_t* __restrict__ act0,
        half_t* __restrict__ act1, float* __restrict__ c0,
        float* __restrict__ c1, float* __restrict__ out,
        unsigned* __restrict__ cnt)
{
    extern __shared__ __align__(16) char smem[];
    half_t* Bst = (half_t*)smem;
    const int tid = threadIdx.x;
    const int wg = blockIdx.x;
    const int lane = tid & 63, wid = tid >> 6;
    const int l15 = lane & 15, l4 = lane >> 4;
    const int grp = wg >> 7, lwg = wg & 127;
    const int ct = lwg >> 2, rt = lwg & 3;

    // load this WG's stationary LSTM weight slice (64 cols x 1024 K, frag-major)
    {
        const half_t* src = (grp ? Wl1p : Wl0p) + (size_t)ct * 65536;
        for (int i = tid; i < 8192; i += 256)
            *(half8*)&Bst[(size_t)i * 8] = *(const half8*)&src[(size_t)i * 8];
    }
    __syncthreads();

    const float* bP = grp ? bP1 : bP0;
    float* cb = grp ? c1 : c0;
    unsigned nb = 0;

    for (int t = 0; t < NT; ++t) {
        const int p = t & 1;
        half_t* a0r = act0 + (size_t)p * (NB * 1024);
        half_t* a0w = act0 + (size_t)(p ^ 1) * (NB * 1024);
        half_t* a1r = act1 + (size_t)p * (NB * 1024);
        half_t* a1w = act1 + (size_t)(p ^ 1) * (NB * 1024);

        // ---- S1: z(t) (WGs 0..63) and y(t-1) (WGs 128..135) ----
        if (grp == 0 && lwg < 64) {
            const int row0 = (lwg & 7) * 32, col0 = (lwg >> 3) * 64;
            const int wr = wid >> 1, wc = wid & 1;
            const int arow = row0 + wr * 16 + l15;
            floatx4 acc[2] = {};
            if (t == 0) {
                // z(0): A = x[0][:,0:512] f32 (fb(0) == x[0][:,384:512]), B = W1h, K=512
                #pragma unroll 2
                for (int kf = 0; kf < 16; ++kf) {
                    const int kk = kf * 32;
                    half8 a = cvt8(x + (size_t)arow * DIN + kk + l4 * 8);
                    #pragma unroll
                    for (int cf = 0; cf < 2; ++cf) {
                        const int n = col0 + wc * 32 + cf * 16 + l15;
                        half8 b = *(const half8*)&W1h[(size_t)n * DIN + kk + l4 * 8];
                        acc[cf] = __builtin_amdgcn_mfma_f32_16x16x32_f16(a, b, acc[cf], 0, 0, 0);
                    }
                }
            } else {
                const float* xt = x + (size_t)t * NB * DIN;
                #pragma unroll 2
                for (int kf = 0; kf < 28; ++kf) {
                    const int kk = kf * 32;
                    half8 a;
                    if (kk < DX) a = cvt8(xt + (size_t)arow * DIN + kk + l4 * 8);
                    else         a = *(const half8*)&a1r[(size_t)arow * 1024 + 512 + (kk - DX) + l4 * 8];
                    #pragma unroll
                    for (int cf = 0; cf < 2; ++cf) {
                        const int n = col0 + wc * 32 + cf * 16 + l15;
                        half8 b = *(const half8*)&W1f[(size_t)n * KZ + kk + l4 * 8];
                        acc[cf] = __builtin_amdgcn_mfma_f32_16x16x32_f16(a, b, acc[cf], 0, 0, 0);
                    }
                }
            }
            #pragma unroll
            for (int cf = 0; cf < 2; ++cf) {
                const int n = col0 + wc * 32 + cf * 16 + l15;
                const float bb = (t == 0) ? b1[n] : b1f[n];
                #pragma unroll
                for (int r = 0; r < 4; ++r) {
                    const int m = row0 + wr * 16 + l4 * 4 + r;
                    a0r[(size_t)m * 1024 + n] = (half_t)fmaxf(acc[cf][r] + bb, 0.f);
                }
            }
        } else if (grp == 1 && lwg < 8 && t >= 1) {
            y_body(a1r, W2h, b2, out + (size_t)(t - 1) * NB * DOUT, lwg, lane, wid);
        }
        grid_barrier(cnt, ++nb * NWG);

        // ---- S2: lstm0 on grp0 (reads [z(t)|h0(t-1)], writes h0 -> a0w[512:] and a1r[0:512])
        if (grp == 0) lstm_body(a0r, Bst, bP, cb, a0w + 512, a1r, ct, rt, lane, wid);
        grid_barrier(cnt, ++nb * NWG);

        // ---- S3: lstm1 on grp1 (reads [h0(t)|h1(t-1)], writes h1 -> a1w[512:])
        if (grp == 1) lstm_body(a1r, Bst, bP, cb, a1w + 512, (half_t*)nullptr, ct, rt, lane, wid);
        grid_barrier(cnt, ++nb * NWG);
    }
    // final y(NT-1): h1(299) lives in act1 parity 0 (300 & 1 == 0)
    if (grp == 1 && lwg < 8)
        y_body(act1, W2h, b2, out + (size_t)(NT - 1) * NB * DOUT, lwg, lane, wid);
}

// ---------------------------------------------------------------------------

extern "C" void kernel_launch(void* const* d_in, const int* in_sizes, int n_in,
                              void* d_out, int out_size, void* d_ws, size_t ws_size,
                              hipStream_t stream) {
    const float* x    = (const float*)d_in[0];
    const float* w1   = (const float*)d_in[1];
    const float* b1   = (const float*)d_in[2];
    const float* w_ih = (const float*)d_in[3];
    const float* w_hh = (const float*)d_in[4];
    const float* b_ih = (const float*)d_in[5];
    const float* b_hh = (const float*)d_in[6];
    const float* w2   = (const float*)d_in[7];
    const float* b2   = (const float*)d_in[8];
    float* out = (float*)d_out;
    (void)in_sizes; (void)n_in; (void)out_size; (void)ws_size;

    char* ws = (char*)d_ws;
    size_t off = 0;
    auto take = [&](size_t bytes) -> char* {
        char* p = ws + off;
        off += (bytes + 255) & ~(size_t)255;
        return p;
    };
    half_t* W1h  = (half_t*)take((size_t)512 * 512 * 2);
    half_t* W2h  = (half_t*)take((size_t)128 * 512 * 2);
    half_t* W1f  = (half_t*)take((size_t)512 * KZ * 2);
    half_t* Wl0p = (half_t*)take((size_t)NG * 1024 * 2);
    half_t* Wl1p = (half_t*)take((size_t)NG * 1024 * 2);
    float*  b1f  = (float*)take((size_t)512 * 4);
    float*  bP0  = (float*)take((size_t)NG * 4);
    float*  bP1  = (float*)take((size_t)NG * 4);
    float*  c0   = (float*)take((size_t)NB * DH * 4);
    float*  c1   = (float*)take((size_t)NB * DH * 4);
    half_t* act0 = (half_t*)take((size_t)2 * NB * 1024 * 2);
    half_t* act1 = (half_t*)take((size_t)2 * NB * 1024 * 2);
    unsigned* cnt = (unsigned*)take(256);

    cvt_f32_f16<<<256, 256, 0, stream>>>(w1, W1h, 512 * 512);
    cvt_f32_f16<<<64, 256, 0, stream>>>(w2, W2h, 128 * 512);
    fold_w1<<<512, 256, 0, stream>>>(w1, w2, b1, b2, W1f, b1f);
    pack_lstm<<<1024, 256, 0, stream>>>(w_ih, w_hh, b_ih, b_hh, Wl0p, bP0);
    pack_lstm<<<1024, 256, 0, stream>>>(w_ih + (size_t)NG * DH, w_hh + (size_t)NG * DH,
                                        b_ih + NG, b_hh + NG, Wl1p, bP1);
    init_all<<<512, 256, 0, stream>>>(act0, act1, c0, c1, cnt);

    hipFuncSetAttribute((const void*)rnn_persistent,
                        hipFuncAttributeMaxDynamicSharedMemorySize, SMEM);

    void* args[] = { (void*)&x, (void*)&W1h, (void*)&W1f, (void*)&b1, (void*)&b1f,
                     (void*)&Wl0p, (void*)&bP0, (void*)&Wl1p, (void*)&bP1,
                     (void*)&W2h, (void*)&b2, (void*)&act0, (void*)&act1,
                     (void*)&c0, (void*)&c1, (void*)&out, (void*)&cnt };
    hipError_t e = hipLaunchCooperativeKernel((void*)rnn_persistent, dim3(NWG), dim3(256),
                                              args, SMEM, stream);
    if (e != hipSuccess) {
        // fallback: plain launch (grid == CU count, 1 WG/CU -> co-resident in practice)
        rnn_persistent<<<dim3(NWG), dim3(256), SMEM, stream>>>(
            x, W1h, W1f, b1, b1f, Wl0p, bP0, Wl1p, bP1, W2h, b2,
            act0, act1, c0, c1, out, cnt);
    }
}

// Round 3
// 15604.395 us; speedup vs baseline: 1.2017x; 1.1958x over previous
//
#include <hip/hip_runtime.h>

typedef _Float16 half_t;
typedef _Float16 half8 __attribute__((ext_vector_type(8)));
typedef float floatx4 __attribute__((ext_vector_type(4)));

#define NT   300
#define NB   256
#define DIN  512
#define DH   512
#define DOUT 128
#define DX   384        // IN - OUT
#define KZ   896        // folded z GEMM K: 384 (x) + 512 (h1)
#define NG   2048       // 4*DH gate rows
#define NWG  256
#define SMEM 131072     // 128KB stationary B slice

// ---------------------------------------------------------------------------
// helpers
// ---------------------------------------------------------------------------

__device__ __forceinline__ float sigm(float x)  { return __builtin_amdgcn_rcpf(1.f + __expf(-x)); }
__device__ __forceinline__ float tanhx(float x) { return 1.f - 2.f * __builtin_amdgcn_rcpf(__expf(2.f * x) + 1.f); }

__device__ __forceinline__ half8 cvt8(const float* s) {
    float4 f0 = *(const float4*)s, f1 = *(const float4*)(s + 4);
    half8 h;
    h[0] = (half_t)f0.x; h[1] = (half_t)f0.y; h[2] = (half_t)f0.z; h[3] = (half_t)f0.w;
    h[4] = (half_t)f1.x; h[5] = (half_t)f1.y; h[6] = (half_t)f1.z; h[7] = (half_t)f1.w;
    return h;
}

// Coherent (agent-scope, L2-bypassing) access helpers. These lower to
// global_load/store with sc1 set: served at the LLC (coherence point for the
// 8 XCDs) with NO cache-wide invalidate/writeback operations.
__device__ __forceinline__ half8 ld_coh_h8(const half_t* p) {
    union { unsigned long long u[2]; half8 h; } r;
    const unsigned long long* q = (const unsigned long long*)p;
    r.u[0] = __hip_atomic_load(q,     __ATOMIC_RELAXED, __HIP_MEMORY_SCOPE_AGENT);
    r.u[1] = __hip_atomic_load(q + 1, __ATOMIC_RELAXED, __HIP_MEMORY_SCOPE_AGENT);
    return r.h;
}
__device__ __forceinline__ void st_coh_h(half_t* p, float v) {
    union { half_t h; unsigned short u; } c; c.h = (half_t)v;
    __hip_atomic_store((unsigned short*)p, c.u, __ATOMIC_RELAXED, __HIP_MEMORY_SCOPE_AGENT);
}

// Fence-free grid barrier: data coherence is handled per-access above; the
// barrier only needs control sync. __syncthreads() drains vmcnt(0) (all this
// WG's coherent stores are at the LLC) before lane 0 signals arrival.
__device__ __forceinline__ void grid_barrier(unsigned* cnt, unsigned target) {
    __syncthreads();
    asm volatile("" ::: "memory");
    if (threadIdx.x == 0) {
        __hip_atomic_fetch_add(cnt, 1u, __ATOMIC_RELAXED, __HIP_MEMORY_SCOPE_AGENT);
        while (__hip_atomic_load(cnt, __ATOMIC_RELAXED, __HIP_MEMORY_SCOPE_AGENT) < target)
            __builtin_amdgcn_s_sleep(1);
    }
    asm volatile("" ::: "memory");
    __syncthreads();
}

// ---------------------------------------------------------------------------
// pre-pass kernels (every call — no caching allowed)
// ---------------------------------------------------------------------------

__global__ void cvt_f32_f16(const float* __restrict__ src, half_t* __restrict__ dst, int n) {
    for (int i = blockIdx.x * blockDim.x + threadIdx.x; i < n; i += gridDim.x * blockDim.x)
        dst[i] = (half_t)src[i];
}

// W1f = [W1x | W1y@W2] (512 x 896) fp16 ; b1f = b1 + W1y@b2
__global__ void fold_w1(const float* __restrict__ w1, const float* __restrict__ w2,
                        const float* __restrict__ b1, const float* __restrict__ b2,
                        half_t* __restrict__ W1f, float* __restrict__ b1f) {
    __shared__ float wy[128], b2s[128];
    const int h = blockIdx.x, tid = threadIdx.x;
    if (tid < 128) { wy[tid] = w1[(size_t)h * DIN + DX + tid]; b2s[tid] = b2[tid]; }
    __syncthreads();
    for (int k = tid; k < DX; k += 256) W1f[(size_t)h * KZ + k] = (half_t)w1[(size_t)h * DIN + k];
    for (int d = tid; d < DH; d += 256) {
        float s = 0.f;
        for (int j = 0; j < 128; ++j) s += wy[j] * w2[(size_t)j * DH + d];
        W1f[(size_t)h * KZ + DX + d] = (half_t)s;
    }
    if (tid == 0) {
        float s = 0.f;
        for (int j = 0; j < 128; ++j) s += wy[j] * b2s[j];
        b1f[h] = b1[h] + s;
    }
}

// Pack [w_ih | w_hh] frag-major with gate interleave.
// packed col n = (d>>4)*64 + g*16 + (d&15); layout unit u = ((ct*32+kf)*4+cf)*64+lane,
// holding half8 of B[k = kf*32+(lane>>4)*8 + j][n = ct*64+cf*16+(lane&15)].
__global__ void pack_lstm(const float* __restrict__ wih, const float* __restrict__ whh,
                          const float* __restrict__ bih, const float* __restrict__ bhh,
                          half_t* __restrict__ Wp, float* __restrict__ biasP) {
    const int u = blockIdx.x * blockDim.x + threadIdx.x;   // 0..262143
    const int lane = u & 63, cf = (u >> 6) & 3, kf = (u >> 8) & 31, ct = u >> 13;
    const int n = ct * 64 + cf * 16 + (lane & 15);
    const int d = ((n >> 6) << 4) | (n & 15);
    const int g = (n >> 4) & 3;
    const int srow = g * DH + d;
    const int k0 = kf * 32 + (lane >> 4) * 8;
    const float* src = (k0 < DH) ? (wih + (size_t)srow * DH + k0)
                                 : (whh + (size_t)srow * DH + (k0 - DH));
    half8 v;
    #pragma unroll
    for (int j = 0; j < 8; ++j) v[j] = (half_t)src[j];
    *(half8*)&Wp[(size_t)u * 8] = v;
    if (kf == 0 && (lane >> 4) == 0) biasP[n] = bih[srow] + bhh[srow];
}

__global__ void init_all(half_t* act0, half_t* act1, float* c0, float* c1, unsigned* cnt) {
    const int step = gridDim.x * blockDim.x;
    const int i0 = blockIdx.x * blockDim.x + threadIdx.x;
    for (int k = i0; k < 2 * NB * 1024; k += step) { act0[k] = (half_t)0.f; act1[k] = (half_t)0.f; }
    for (int k = i0; k < NB * DH; k += step) { c0[k] = 0.f; c1[k] = 0.f; }
    if (i0 == 0) *cnt = 0u;
}

// ---------------------------------------------------------------------------
// persistent cooperative kernel
// 256 WGs x 256 thr (1/CU). grp0 = WGs 0..127 (lstm0), grp1 = 128..255 (lstm1).
// Per step: S1 { z(t) on WGs 0..63 ; y(t-1) on WGs 128..135 } | S2 lstm0 | S3 lstm1.
// ---------------------------------------------------------------------------

__device__ __forceinline__ void lstm_body(const half_t* __restrict__ A, const half_t* __restrict__ Bst,
                                          const float* __restrict__ bP, float* __restrict__ cb,
                                          half_t* __restrict__ hd1, half_t* __restrict__ hd2,
                                          int ct, int rt, int lane, int wid) {
    const int l15 = lane & 15, l4 = lane >> 4;
    const int wrow = rt * 64 + wid * 16;
    floatx4 acc[4] = {};
    #pragma unroll 8
    for (int kf = 0; kf < 32; ++kf) {
        const int kk = kf * 32;
        half8 a = ld_coh_h8(&A[(size_t)(wrow + l15) * 1024 + kk + l4 * 8]);
        #pragma unroll
        for (int cf = 0; cf < 4; ++cf) {
            half8 b = *(const half8*)&Bst[(size_t)((kf * 4 + cf) * 64 + lane) * 8];
            acc[cf] = __builtin_amdgcn_mfma_f32_16x16x32_f16(a, b, acc[cf], 0, 0, 0);
        }
    }
    const int d = ct * 16 + l15;
    const float bi = bP[ct * 64 + l15], bf_ = bP[ct * 64 + 16 + l15];
    const float bg = bP[ct * 64 + 32 + l15], bo = bP[ct * 64 + 48 + l15];
    #pragma unroll
    for (int r = 0; r < 4; ++r) {
        const int m = wrow + l4 * 4 + r;
        const float gi = acc[0][r] + bi, gf = acc[1][r] + bf_;
        const float gg = acc[2][r] + bg, go = acc[3][r] + bo;
        const float si = sigm(gi), sf = sigm(gf), so = sigm(go);
        const float cn = sf * cb[(size_t)m * DH + d] + si * tanhx(gg);
        const float hn = so * tanhx(cn);
        cb[(size_t)m * DH + d] = cn;   // WG-private: stays on cached path
        st_coh_h(&hd1[(size_t)m * 1024 + d], hn);
        if (hd2) st_coh_h(&hd2[(size_t)m * 1024 + d], hn);
    }
}

__device__ __forceinline__ void y_body(const half_t* __restrict__ a1r, const half_t* __restrict__ W2h,
                                       const float* __restrict__ b2, float* __restrict__ yo,
                                       int lwg, int lane, int wid) {
    const int l15 = lane & 15, l4 = lane >> 4;
    const int row0 = lwg * 32;
    const int wr = wid >> 1, wc = wid & 1;
    const int arow = row0 + wr * 16 + l15;
    floatx4 acc[4] = {};
    #pragma unroll 4
    for (int kf = 0; kf < 16; ++kf) {
        const int kk = kf * 32;
        half8 a = ld_coh_h8(&a1r[(size_t)arow * 1024 + 512 + kk + l4 * 8]);
        #pragma unroll
        for (int cf = 0; cf < 4; ++cf) {
            const int n = wc * 64 + cf * 16 + l15;
            half8 b = *(const half8*)&W2h[(size_t)n * DH + kk + l4 * 8];
            acc[cf] = __builtin_amdgcn_mfma_f32_16x16x32_f16(a, b, acc[cf], 0, 0, 0);
        }
    }
    #pragma unroll
    for (int cf = 0; cf < 4; ++cf) {
        const int n = wc * 64 + cf * 16 + l15;
        const float bb = b2[n];
        #pragma unroll
        for (int r = 0; r < 4; ++r) {
            const int m = row0 + wr * 16 + l4 * 4 + r;
            yo[(size_t)m * DOUT + n] = acc[cf][r] + bb;   // plain: visible at kernel end
        }
    }
}

__global__ void __launch_bounds__(256, 1) rnn_persistent(
        const float* __restrict__ x, const half_t* __restrict__ W1h,
        const half_t* __restrict__ W1f, const float* __restrict__ b1,
        const float* __restrict__ b1f, const half_t* __restrict__ Wl0p,
        const float* __restrict__ bP0, const half_t* __restrict__ Wl1p,
        const float* __restrict__ bP1, const half_t* __restrict__ W2h,
        const float* __restrict__ b2, half_t* __restrict__ act0,
        half_t* __restrict__ act1, float* __restrict__ c0,
        float* __restrict__ c1, float* __restrict__ out,
        unsigned* __restrict__ cnt)
{
    extern __shared__ __align__(16) char smem[];
    half_t* Bst = (half_t*)smem;
    const int tid = threadIdx.x;
    const int wg = blockIdx.x;
    const int lane = tid & 63, wid = tid >> 6;
    const int l15 = lane & 15, l4 = lane >> 4;
    const int grp = wg >> 7, lwg = wg & 127;
    const int ct = lwg >> 2, rt = lwg & 3;

    // load this WG's stationary LSTM weight slice (64 cols x 1024 K, frag-major)
    {
        const half_t* src = (grp ? Wl1p : Wl0p) + (size_t)ct * 65536;
        for (int i = tid; i < 8192; i += 256)
            *(half8*)&Bst[(size_t)i * 8] = *(const half8*)&src[(size_t)i * 8];
    }
    __syncthreads();

    const float* bP = grp ? bP1 : bP0;
    float* cb = grp ? c1 : c0;
    unsigned nb = 0;

    for (int t = 0; t < NT; ++t) {
        const int p = t & 1;
        half_t* a0r = act0 + (size_t)p * (NB * 1024);
        half_t* a0w = act0 + (size_t)(p ^ 1) * (NB * 1024);
        half_t* a1r = act1 + (size_t)p * (NB * 1024);
        half_t* a1w = act1 + (size_t)(p ^ 1) * (NB * 1024);

        // ---- S1: z(t) (WGs 0..63) and y(t-1) (WGs 128..135) ----
        if (grp == 0 && lwg < 64) {
            const int row0 = (lwg & 7) * 32, col0 = (lwg >> 3) * 64;
            const int wr = wid >> 1, wc = wid & 1;
            const int arow = row0 + wr * 16 + l15;
            floatx4 acc[2] = {};
            if (t == 0) {
                // z(0): A = x[0][:,0:512] f32 (fb(0) == x[0][:,384:512]), B = W1h, K=512
                #pragma unroll 2
                for (int kf = 0; kf < 16; ++kf) {
                    const int kk = kf * 32;
                    half8 a = cvt8(x + (size_t)arow * DIN + kk + l4 * 8);
                    #pragma unroll
                    for (int cf = 0; cf < 2; ++cf) {
                        const int n = col0 + wc * 32 + cf * 16 + l15;
                        half8 b = *(const half8*)&W1h[(size_t)n * DIN + kk + l4 * 8];
                        acc[cf] = __builtin_amdgcn_mfma_f32_16x16x32_f16(a, b, acc[cf], 0, 0, 0);
                    }
                }
            } else {
                const float* xt = x + (size_t)t * NB * DIN;
                #pragma unroll 4
                for (int kf = 0; kf < 28; ++kf) {
                    const int kk = kf * 32;
                    half8 a;
                    if (kk < DX) a = cvt8(xt + (size_t)arow * DIN + kk + l4 * 8);
                    else         a = ld_coh_h8(&a1r[(size_t)arow * 1024 + 512 + (kk - DX) + l4 * 8]);
                    #pragma unroll
                    for (int cf = 0; cf < 2; ++cf) {
                        const int n = col0 + wc * 32 + cf * 16 + l15;
                        half8 b = *(const half8*)&W1f[(size_t)n * KZ + kk + l4 * 8];
                        acc[cf] = __builtin_amdgcn_mfma_f32_16x16x32_f16(a, b, acc[cf], 0, 0, 0);
                    }
                }
            }
            #pragma unroll
            for (int cf = 0; cf < 2; ++cf) {
                const int n = col0 + wc * 32 + cf * 16 + l15;
                const float bb = (t == 0) ? b1[n] : b1f[n];
                #pragma unroll
                for (int r = 0; r < 4; ++r) {
                    const int m = row0 + wr * 16 + l4 * 4 + r;
                    st_coh_h(&a0r[(size_t)m * 1024 + n], fmaxf(acc[cf][r] + bb, 0.f));
                }
            }
        } else if (grp == 1 && lwg < 8 && t >= 1) {
            y_body(a1r, W2h, b2, out + (size_t)(t - 1) * NB * DOUT, lwg, lane, wid);
        }
        grid_barrier(cnt, ++nb * NWG);

        // ---- S2: lstm0 on grp0 (reads [z(t)|h0(t-1)], writes h0 -> a0w[512:] and a1r[0:512])
        if (grp == 0) lstm_body(a0r, Bst, bP, cb, a0w + 512, a1r, ct, rt, lane, wid);
        grid_barrier(cnt, ++nb * NWG);

        // ---- S3: lstm1 on grp1 (reads [h0(t)|h1(t-1)], writes h1 -> a1w[512:])
        if (grp == 1) lstm_body(a1r, Bst, bP, cb, a1w + 512, (half_t*)nullptr, ct, rt, lane, wid);
        grid_barrier(cnt, ++nb * NWG);
    }
    // final y(NT-1): h1(299) lives in act1 parity 0 (300 & 1 == 0)
    if (grp == 1 && lwg < 8)
        y_body(act1, W2h, b2, out + (size_t)(NT - 1) * NB * DOUT, lwg, lane, wid);
}

// ---------------------------------------------------------------------------

extern "C" void kernel_launch(void* const* d_in, const int* in_sizes, int n_in,
                              void* d_out, int out_size, void* d_ws, size_t ws_size,
                              hipStream_t stream) {
    const float* x    = (const float*)d_in[0];
    const float* w1   = (const float*)d_in[1];
    const float* b1   = (const float*)d_in[2];
    const float* w_ih = (const float*)d_in[3];
    const float* w_hh = (const float*)d_in[4];
    const float* b_ih = (const float*)d_in[5];
    const float* b_hh = (const float*)d_in[6];
    const float* w2   = (const float*)d_in[7];
    const float* b2   = (const float*)d_in[8];
    float* out = (float*)d_out;
    (void)in_sizes; (void)n_in; (void)out_size; (void)ws_size;

    char* ws = (char*)d_ws;
    size_t off = 0;
    auto take = [&](size_t bytes) -> char* {
        char* p = ws + off;
        off += (bytes + 255) & ~(size_t)255;
        return p;
    };
    half_t* W1h  = (half_t*)take((size_t)512 * 512 * 2);
    half_t* W2h  = (half_t*)take((size_t)128 * 512 * 2);
    half_t* W1f  = (half_t*)take((size_t)512 * KZ * 2);
    half_t* Wl0p = (half_t*)take((size_t)NG * 1024 * 2);
    half_t* Wl1p = (half_t*)take((size_t)NG * 1024 * 2);
    float*  b1f  = (float*)take((size_t)512 * 4);
    float*  bP0  = (float*)take((size_t)NG * 4);
    float*  bP1  = (float*)take((size_t)NG * 4);
    float*  c0   = (float*)take((size_t)NB * DH * 4);
    float*  c1   = (float*)take((size_t)NB * DH * 4);
    half_t* act0 = (half_t*)take((size_t)2 * NB * 1024 * 2);
    half_t* act1 = (half_t*)take((size_t)2 * NB * 1024 * 2);
    unsigned* cnt = (unsigned*)take(256);

    cvt_f32_f16<<<256, 256, 0, stream>>>(w1, W1h, 512 * 512);
    cvt_f32_f16<<<64, 256, 0, stream>>>(w2, W2h, 128 * 512);
    fold_w1<<<512, 256, 0, stream>>>(w1, w2, b1, b2, W1f, b1f);
    pack_lstm<<<1024, 256, 0, stream>>>(w_ih, w_hh, b_ih, b_hh, Wl0p, bP0);
    pack_lstm<<<1024, 256, 0, stream>>>(w_ih + (size_t)NG * DH, w_hh + (size_t)NG * DH,
                                        b_ih + NG, b_hh + NG, Wl1p, bP1);
    init_all<<<512, 256, 0, stream>>>(act0, act1, c0, c1, cnt);

    hipFuncSetAttribute((const void*)rnn_persistent,
                        hipFuncAttributeMaxDynamicSharedMemorySize, SMEM);

    void* args[] = { (void*)&x, (void*)&W1h, (void*)&W1f, (void*)&b1, (void*)&b1f,
                     (void*)&Wl0p, (void*)&bP0, (void*)&Wl1p, (void*)&bP1,
                     (void*)&W2h, (void*)&b2, (void*)&act0, (void*)&act1,
                     (void*)&c0, (void*)&c1, (void*)&out, (void*)&cnt };
    hipError_t e = hipLaunchCooperativeKernel((void*)rnn_persistent, dim3(NWG), dim3(256),
                                              args, SMEM, stream);
    if (e != hipSuccess) {
        // fallback: plain launch (grid == CU count, 1 WG/CU -> co-resident in practice)
        rnn_persistent<<<dim3(NWG), dim3(256), SMEM, stream>>>(
            x, W1h, W1f, b1, b1f, Wl0p, bP0, Wl1p, bP1, W2h, b2,
            act0, act1, c0, c1, out, cnt);
    }
}

// Round 5
// 9818.881 us; speedup vs baseline: 1.9098x; 1.5892x over previous
//
#include <hip/hip_runtime.h>

typedef _Float16 half_t;
typedef _Float16 half8 __attribute__((ext_vector_type(8)));
typedef float floatx4 __attribute__((ext_vector_type(4)));

#define NT   300
#define NB   256
#define DIN  512
#define DH   512
#define DOUT 128
#define DX   384        // IN - OUT
#define KZ   896        // folded z GEMM K: 384 (x) + 512 (h1)
#define NG   2048       // 4*DH gate rows
#define NWG  256
#define SMEM 131072     // 128KB stationary B slice

// counted vmem wait + scheduling fence (rule #18: MFMA can hoist past bare asm waitcnt)
#define WAITVM(N) do { asm volatile("s_waitcnt vmcnt(" #N ")" ::: "memory"); \
                       __builtin_amdgcn_sched_barrier(0); } while (0)

// ---------------------------------------------------------------------------
// helpers
// ---------------------------------------------------------------------------

__device__ __forceinline__ float sigm(float x)  { return __builtin_amdgcn_rcpf(1.f + __expf(-x)); }
__device__ __forceinline__ float tanhx(float x) { return 1.f - 2.f * __builtin_amdgcn_rcpf(__expf(2.f * x) + 1.f); }

__device__ __forceinline__ half8 cvt8(const float* s) {
    float4 f0 = *(const float4*)s, f1 = *(const float4*)(s + 4);
    half8 h;
    h[0] = (half_t)f0.x; h[1] = (half_t)f0.y; h[2] = (half_t)f0.z; h[3] = (half_t)f0.w;
    h[4] = (half_t)f1.x; h[5] = (half_t)f1.y; h[6] = (half_t)f1.z; h[7] = (half_t)f1.w;
    return h;
}

// 8x 16B coherent loads (bypass L1/L2, served at LLC), single base + imm offsets,
// NO waitcnt inside — caller pipelines with counted WAITVM.
__device__ __forceinline__ void ldA8(const half_t* b, half8& r0, half8& r1, half8& r2, half8& r3,
                                     half8& r4, half8& r5, half8& r6, half8& r7) {
    asm volatile(
        "global_load_dwordx4 %0, %8, off sc0 sc1\n\t"
        "global_load_dwordx4 %1, %8, off offset:64 sc0 sc1\n\t"
        "global_load_dwordx4 %2, %8, off offset:128 sc0 sc1\n\t"
        "global_load_dwordx4 %3, %8, off offset:192 sc0 sc1\n\t"
        "global_load_dwordx4 %4, %8, off offset:256 sc0 sc1\n\t"
        "global_load_dwordx4 %5, %8, off offset:320 sc0 sc1\n\t"
        "global_load_dwordx4 %6, %8, off offset:384 sc0 sc1\n\t"
        "global_load_dwordx4 %7, %8, off offset:448 sc0 sc1"
        : "=&v"(r0), "=&v"(r1), "=&v"(r2), "=&v"(r3),
          "=&v"(r4), "=&v"(r5), "=&v"(r6), "=&v"(r7)
        : "v"(b) : "memory");
}

__device__ __forceinline__ void st_coh_h(half_t* p, float v) {
    union { half_t h; unsigned short u; } c; c.h = (half_t)v;
    unsigned w = c.u;
    asm volatile("global_store_short %0, %1, off sc0 sc1" :: "v"(p), "v"(w) : "memory");
}

__device__ __forceinline__ unsigned ld_flag(const unsigned* p) {
    unsigned v;
    asm volatile("global_load_dword %0, %1, off sc0 sc1\n\ts_waitcnt vmcnt(0)"
                 : "=v"(v) : "v"(p) : "memory");
    return v;
}
__device__ __forceinline__ void st_flag(unsigned* p, unsigned v) {
    asm volatile("global_store_dword %0, %1, off sc0 sc1" :: "v"(p), "v"(v) : "memory");
}

// Two-level flag barrier: per-WG arrival slots (64B apart, parallel stores),
// WG0's threads poll them in parallel, one release flag. No RMW anywhere.
__device__ __forceinline__ void grid_barrier(unsigned* arrive, unsigned* release, unsigned phase) {
    asm volatile("s_waitcnt vmcnt(0) lgkmcnt(0)" ::: "memory");   // own stores visible at LLC
    __syncthreads();
    if (blockIdx.x == 0) {
        const int tid = threadIdx.x;
        if (tid > 0)
            while (ld_flag(arrive + tid * 16) < phase) {}
        __syncthreads();
        if (tid == 0) st_flag(release, phase);
    } else {
        if (threadIdx.x == 0) {
            st_flag(arrive + blockIdx.x * 16, phase);
            while (ld_flag(release) < phase) {}
        }
        __syncthreads();
    }
}

// ---------------------------------------------------------------------------
// pre-pass kernels (every call — no caching allowed)
// ---------------------------------------------------------------------------

__global__ void cvt_f32_f16(const float* __restrict__ src, half_t* __restrict__ dst, int n) {
    for (int i = blockIdx.x * blockDim.x + threadIdx.x; i < n; i += gridDim.x * blockDim.x)
        dst[i] = (half_t)src[i];
}

// W1f = [W1x | W1y@W2] (512 x 896) fp16 ; b1f = b1 + W1y@b2
__global__ void fold_w1(const float* __restrict__ w1, const float* __restrict__ w2,
                        const float* __restrict__ b1, const float* __restrict__ b2,
                        half_t* __restrict__ W1f, float* __restrict__ b1f) {
    __shared__ float wy[128], b2s[128];
    const int h = blockIdx.x, tid = threadIdx.x;
    if (tid < 128) { wy[tid] = w1[(size_t)h * DIN + DX + tid]; b2s[tid] = b2[tid]; }
    __syncthreads();
    for (int k = tid; k < DX; k += 256) W1f[(size_t)h * KZ + k] = (half_t)w1[(size_t)h * DIN + k];
    for (int d = tid; d < DH; d += 256) {
        float s = 0.f;
        for (int j = 0; j < 128; ++j) s += wy[j] * w2[(size_t)j * DH + d];
        W1f[(size_t)h * KZ + DX + d] = (half_t)s;
    }
    if (tid == 0) {
        float s = 0.f;
        for (int j = 0; j < 128; ++j) s += wy[j] * b2s[j];
        b1f[h] = b1[h] + s;
    }
}

// Pack [w_ih | w_hh] frag-major with gate interleave.
// packed col n = (d>>4)*64 + g*16 + (d&15); layout unit u = ((ct*32+kf)*4+cf)*64+lane,
// holding half8 of B[k = kf*32+(lane>>4)*8 + j][n = ct*64+cf*16+(lane&15)].
__global__ void pack_lstm(const float* __restrict__ wih, const float* __restrict__ whh,
                          const float* __restrict__ bih, const float* __restrict__ bhh,
                          half_t* __restrict__ Wp, float* __restrict__ biasP) {
    const int u = blockIdx.x * blockDim.x + threadIdx.x;   // 0..262143
    const int lane = u & 63, cf = (u >> 6) & 3, kf = (u >> 8) & 31, ct = u >> 13;
    const int n = ct * 64 + cf * 16 + (lane & 15);
    const int d = ((n >> 6) << 4) | (n & 15);
    const int g = (n >> 4) & 3;
    const int srow = g * DH + d;
    const int k0 = kf * 32 + (lane >> 4) * 8;
    const float* src = (k0 < DH) ? (wih + (size_t)srow * DH + k0)
                                 : (whh + (size_t)srow * DH + (k0 - DH));
    half8 v;
    #pragma unroll
    for (int j = 0; j < 8; ++j) v[j] = (half_t)src[j];
    *(half8*)&Wp[(size_t)u * 8] = v;
    if (kf == 0 && (lane >> 4) == 0) biasP[n] = bih[srow] + bhh[srow];
}

__global__ void init_all(half_t* act0, half_t* act1, float* c0, float* c1,
                         unsigned* arrive, unsigned* release) {
    const int step = gridDim.x * blockDim.x;
    const int i0 = blockIdx.x * blockDim.x + threadIdx.x;
    for (int k = i0; k < 2 * NB * 1024; k += step) { act0[k] = (half_t)0.f; act1[k] = (half_t)0.f; }
    for (int k = i0; k < NB * DH; k += step) { c0[k] = 0.f; c1[k] = 0.f; }
    for (int k = i0; k < NWG * 16; k += step) arrive[k] = 0u;
    if (i0 == 0) *release = 0u;
}

// ---------------------------------------------------------------------------
// persistent cooperative kernel
// 256 WGs x 256 thr (1/CU). grp0 = WGs 0..127 (lstm0), grp1 = 128..255 (lstm1).
// Per step: S1 { z(t) on WGs 0..63 ; y(t-1) on WGs 128..135 } | S2 lstm0 | S3 lstm1.
// ---------------------------------------------------------------------------

// 8 kf-steps (K=256) of the lstm GEMM from preloaded A-frags ARR[0..7]
// Bst unit u = (kf*4+cf)*64+lane holds half8 at element offset u*8:
//   (kf*4+cf)*512 + lane*8   [half elements]
#define QUAD8(ARR, KB) \
    _Pragma("unroll") \
    for (int j = 0; j < 8; ++j) { \
        _Pragma("unroll") \
        for (int cf = 0; cf < 4; ++cf) { \
            half8 b = *(const half8*)&Bst[(size_t)((((KB) + j) * 4 + cf) * 64 + lane) * 8]; \
            acc[cf] = __builtin_amdgcn_mfma_f32_16x16x32_f16(ARR[j], b, acc[cf], 0, 0, 0); \
        } \
    }

__device__ __forceinline__ void lstm_body(const half_t* __restrict__ A, const half_t* __restrict__ Bst,
                                          const float* __restrict__ bP, float* __restrict__ cb,
                                          half_t* __restrict__ hd1, half_t* __restrict__ hd2,
                                          int ct, int rt, int lane, int wid) {
    const int l15 = lane & 15, l4 = lane >> 4;
    const int wrow = rt * 64 + wid * 16;
    const half_t* Ab = A + (size_t)(wrow + l15) * 1024 + l4 * 8;

    half8 p[8], q[8];
    floatx4 acc[4] = {};
    ldA8(Ab,       p[0], p[1], p[2], p[3], p[4], p[5], p[6], p[7]);
    ldA8(Ab + 256, q[0], q[1], q[2], q[3], q[4], q[5], q[6], q[7]);
    WAITVM(8);                 // p ready
    QUAD8(p, 0);
    ldA8(Ab + 512, p[0], p[1], p[2], p[3], p[4], p[5], p[6], p[7]);
    WAITVM(8);                 // q ready (8 newest = p-batch2)
    QUAD8(q, 8);
    ldA8(Ab + 768, q[0], q[1], q[2], q[3], q[4], q[5], q[6], q[7]);
    WAITVM(8);                 // p-batch2 ready
    QUAD8(p, 16);
    WAITVM(0);                 // q-batch2 ready
    QUAD8(q, 24);

    const int d = ct * 16 + l15;
    const float bi = bP[ct * 64 + l15], bf_ = bP[ct * 64 + 16 + l15];
    const float bg = bP[ct * 64 + 32 + l15], bo = bP[ct * 64 + 48 + l15];
    #pragma unroll
    for (int r = 0; r < 4; ++r) {
        const int m = wrow + l4 * 4 + r;
        const float gi = acc[0][r] + bi, gf = acc[1][r] + bf_;
        const float gg = acc[2][r] + bg, go = acc[3][r] + bo;
        const float si = sigm(gi), sf = sigm(gf), so = sigm(go);
        const float cn = sf * cb[(size_t)m * DH + d] + si * tanhx(gg);
        const float hn = so * tanhx(cn);
        cb[(size_t)m * DH + d] = cn;   // WG-private: cached path
        st_coh_h(&hd1[(size_t)m * 1024 + d], hn);
        if (hd2) st_coh_h(&hd2[(size_t)m * 1024 + d], hn);
    }
}

__device__ __forceinline__ void y_body(const half_t* __restrict__ a1r, const half_t* __restrict__ W2h,
                                       const float* __restrict__ b2, float* __restrict__ yo,
                                       int lwg, int lane, int wid) {
    const int l15 = lane & 15, l4 = lane >> 4;
    const int row0 = lwg * 32;
    const int wr = wid >> 1, wc = wid & 1;
    const int arow = row0 + wr * 16 + l15;
    const half_t* hb = a1r + (size_t)arow * 1024 + 512 + l4 * 8;
    half8 p[8], q[8];
    ldA8(hb,       p[0], p[1], p[2], p[3], p[4], p[5], p[6], p[7]);
    ldA8(hb + 256, q[0], q[1], q[2], q[3], q[4], q[5], q[6], q[7]);
    floatx4 acc[4] = {};
    WAITVM(0);
    #pragma unroll
    for (int j = 0; j < 16; ++j) {
        half8 a = (j < 8) ? p[j & 7] : q[j & 7];
        #pragma unroll
        for (int cf = 0; cf < 4; ++cf) {
            const int n = wc * 64 + cf * 16 + l15;
            half8 b = *(const half8*)&W2h[(size_t)n * DH + j * 32 + l4 * 8];
            acc[cf] = __builtin_amdgcn_mfma_f32_16x16x32_f16(a, b, acc[cf], 0, 0, 0);
        }
    }
    #pragma unroll
    for (int cf = 0; cf < 4; ++cf) {
        const int n = wc * 64 + cf * 16 + l15;
        const float bb = b2[n];
        #pragma unroll
        for (int r = 0; r < 4; ++r) {
            const int m = row0 + wr * 16 + l4 * 4 + r;
            yo[(size_t)m * DOUT + n] = acc[cf][r] + bb;   // plain: visible at kernel end
        }
    }
}

__global__ void __launch_bounds__(256, 1) rnn_persistent(
        const float* __restrict__ x, const half_t* __restrict__ W1h,
        const half_t* __restrict__ W1f, const float* __restrict__ b1,
        const float* __restrict__ b1f, const half_t* __restrict__ Wl0p,
        const float* __restrict__ bP0, const half_t* __restrict__ Wl1p,
        const float* __restrict__ bP1, const half_t* __restrict__ W2h,
        const float* __restrict__ b2, half_t* __restrict__ act0,
        half_t* __restrict__ act1, float* __restrict__ c0,
        float* __restrict__ c1, float* __restrict__ out,
        unsigned* __restrict__ arrive, unsigned* __restrict__ release)
{
    extern __shared__ __align__(16) char smem[];
    half_t* Bst = (half_t*)smem;
    const int tid = threadIdx.x;
    const int wg = blockIdx.x;
    const int lane = tid & 63, wid = tid >> 6;
    const int l15 = lane & 15, l4 = lane >> 4;
    const int grp = wg >> 7, lwg = wg & 127;
    const int ct = lwg >> 2, rt = lwg & 3;

    // load this WG's stationary LSTM weight slice (64 cols x 1024 K, frag-major)
    {
        const half_t* src = (grp ? Wl1p : Wl0p) + (size_t)ct * 65536;
        for (int i = tid; i < 8192; i += 256)
            *(half8*)&Bst[(size_t)i * 8] = *(const half8*)&src[(size_t)i * 8];
    }
    __syncthreads();

    const float* bP = grp ? bP1 : bP0;
    float* cb = grp ? c1 : c0;
    unsigned ph = 0;

    for (int t = 0; t < NT; ++t) {
        const int p2 = t & 1;
        half_t* a0r = act0 + (size_t)p2 * (NB * 1024);
        half_t* a0w = act0 + (size_t)(p2 ^ 1) * (NB * 1024);
        half_t* a1r = act1 + (size_t)p2 * (NB * 1024);
        half_t* a1w = act1 + (size_t)(p2 ^ 1) * (NB * 1024);

        // ---- S1: z(t) (WGs 0..63) and y(t-1) (WGs 128..135) ----
        if (grp == 0 && lwg < 64) {
            const int row0 = (lwg & 7) * 32, col0 = (lwg >> 3) * 64;
            const int wr = wid >> 1, wc = wid & 1;
            const int arow = row0 + wr * 16 + l15;
            floatx4 acc[2] = {};
            if (t == 0) {
                // z(0): A = x[0][:,0:512] f32 (fb(0) == x[0][:,384:512]), B = W1h, K=512
                #pragma unroll 2
                for (int kf = 0; kf < 16; ++kf) {
                    const int kk = kf * 32;
                    half8 a = cvt8(x + (size_t)arow * DIN + kk + l4 * 8);
                    #pragma unroll
                    for (int cf = 0; cf < 2; ++cf) {
                        const int n = col0 + wc * 32 + cf * 16 + l15;
                        half8 b = *(const half8*)&W1h[(size_t)n * DIN + kk + l4 * 8];
                        acc[cf] = __builtin_amdgcn_mfma_f32_16x16x32_f16(a, b, acc[cf], 0, 0, 0);
                    }
                }
            } else {
                const float* xt = x + (size_t)t * NB * DIN;
                const half_t* hb = a1r + (size_t)arow * 1024 + 512 + l4 * 8;
                half8 p[8], q[8];
                ldA8(hb,       p[0], p[1], p[2], p[3], p[4], p[5], p[6], p[7]);
                ldA8(hb + 256, q[0], q[1], q[2], q[3], q[4], q[5], q[6], q[7]);
                // x-part (K 0..383) with plain cached loads, hides h-load latency
                #pragma unroll 4
                for (int kf = 0; kf < 12; ++kf) {
                    half8 a = cvt8(xt + (size_t)arow * DIN + kf * 32 + l4 * 8);
                    #pragma unroll
                    for (int cf = 0; cf < 2; ++cf) {
                        const int n = col0 + wc * 32 + cf * 16 + l15;
                        half8 b = *(const half8*)&W1f[(size_t)n * KZ + kf * 32 + l4 * 8];
                        acc[cf] = __builtin_amdgcn_mfma_f32_16x16x32_f16(a, b, acc[cf], 0, 0, 0);
                    }
                }
                WAITVM(0);
                #pragma unroll
                for (int j = 0; j < 16; ++j) {
                    const int kf = 12 + j;
                    half8 a = (j < 8) ? p[j & 7] : q[j & 7];
                    #pragma unroll
                    for (int cf = 0; cf < 2; ++cf) {
                        const int n = col0 + wc * 32 + cf * 16 + l15;
                        half8 b = *(const half8*)&W1f[(size_t)n * KZ + kf * 32 + l4 * 8];
                        acc[cf] = __builtin_amdgcn_mfma_f32_16x16x32_f16(a, b, acc[cf], 0, 0, 0);
                    }
                }
            }
            #pragma unroll
            for (int cf = 0; cf < 2; ++cf) {
                const int n = col0 + wc * 32 + cf * 16 + l15;
                const float bb = (t == 0) ? b1[n] : b1f[n];
                #pragma unroll
                for (int r = 0; r < 4; ++r) {
                    const int m = row0 + wr * 16 + l4 * 4 + r;
                    st_coh_h(&a0r[(size_t)m * 1024 + n], fmaxf(acc[cf][r] + bb, 0.f));
                }
            }
        } else if (grp == 1 && lwg < 8 && t >= 1) {
            y_body(a1r, W2h, b2, out + (size_t)(t - 1) * NB * DOUT, lwg, lane, wid);
        }
        grid_barrier(arrive, release, ++ph);

        // ---- S2: lstm0 on grp0 (reads [z(t)|h0(t-1)], writes h0 -> a0w[512:] and a1r[0:512])
        if (grp == 0) lstm_body(a0r, Bst, bP, cb, a0w + 512, a1r, ct, rt, lane, wid);
        grid_barrier(arrive, release, ++ph);

        // ---- S3: lstm1 on grp1 (reads [h0(t)|h1(t-1)], writes h1 -> a1w[512:])
        if (grp == 1) lstm_body(a1r, Bst, bP, cb, a1w + 512, (half_t*)nullptr, ct, rt, lane, wid);
        grid_barrier(arrive, release, ++ph);
    }
    // final y(NT-1): h1(299) lives in act1 parity 0 (300 & 1 == 0)
    if (grp == 1 && lwg < 8)
        y_body(act1, W2h, b2, out + (size_t)(NT - 1) * NB * DOUT, lwg, lane, wid);
}

// ---------------------------------------------------------------------------

extern "C" void kernel_launch(void* const* d_in, const int* in_sizes, int n_in,
                              void* d_out, int out_size, void* d_ws, size_t ws_size,
                              hipStream_t stream) {
    const float* x    = (const float*)d_in[0];
    const float* w1   = (const float*)d_in[1];
    const float* b1   = (const float*)d_in[2];
    const float* w_ih = (const float*)d_in[3];
    const float* w_hh = (const float*)d_in[4];
    const float* b_ih = (const float*)d_in[5];
    const float* b_hh = (const float*)d_in[6];
    const float* w2   = (const float*)d_in[7];
    const float* b2   = (const float*)d_in[8];
    float* out = (float*)d_out;
    (void)in_sizes; (void)n_in; (void)out_size; (void)ws_size;

    char* ws = (char*)d_ws;
    size_t off = 0;
    auto take = [&](size_t bytes) -> char* {
        char* p = ws + off;
        off += (bytes + 255) & ~(size_t)255;
        return p;
    };
    half_t* W1h  = (half_t*)take((size_t)512 * 512 * 2);
    half_t* W2h  = (half_t*)take((size_t)128 * 512 * 2);
    half_t* W1f  = (half_t*)take((size_t)512 * KZ * 2);
    half_t* Wl0p = (half_t*)take((size_t)NG * 1024 * 2);
    half_t* Wl1p = (half_t*)take((size_t)NG * 1024 * 2);
    float*  b1f  = (float*)take((size_t)512 * 4);
    float*  bP0  = (float*)take((size_t)NG * 4);
    float*  bP1  = (float*)take((size_t)NG * 4);
    float*  c0   = (float*)take((size_t)NB * DH * 4);
    float*  c1   = (float*)take((size_t)NB * DH * 4);
    half_t* act0 = (half_t*)take((size_t)2 * NB * 1024 * 2);
    half_t* act1 = (half_t*)take((size_t)2 * NB * 1024 * 2);
    unsigned* arrive  = (unsigned*)take((size_t)NWG * 16 * 4);
    unsigned* release = (unsigned*)take(256);

    cvt_f32_f16<<<256, 256, 0, stream>>>(w1, W1h, 512 * 512);
    cvt_f32_f16<<<64, 256, 0, stream>>>(w2, W2h, 128 * 512);
    fold_w1<<<512, 256, 0, stream>>>(w1, w2, b1, b2, W1f, b1f);
    pack_lstm<<<1024, 256, 0, stream>>>(w_ih, w_hh, b_ih, b_hh, Wl0p, bP0);
    pack_lstm<<<1024, 256, 0, stream>>>(w_ih + (size_t)NG * DH, w_hh + (size_t)NG * DH,
                                        b_ih + NG, b_hh + NG, Wl1p, bP1);
    init_all<<<512, 256, 0, stream>>>(act0, act1, c0, c1, arrive, release);

    hipFuncSetAttribute((const void*)rnn_persistent,
                        hipFuncAttributeMaxDynamicSharedMemorySize, SMEM);

    void* args[] = { (void*)&x, (void*)&W1h, (void*)&W1f, (void*)&b1, (void*)&b1f,
                     (void*)&Wl0p, (void*)&bP0, (void*)&Wl1p, (void*)&bP1,
                     (void*)&W2h, (void*)&b2, (void*)&act0, (void*)&act1,
                     (void*)&c0, (void*)&c1, (void*)&out, (void*)&arrive, (void*)&release };
    hipError_t e = hipLaunchCooperativeKernel((void*)rnn_persistent, dim3(NWG), dim3(256),
                                              args, SMEM, stream);
    if (e != hipSuccess) {
        // fallback: plain launch (grid == CU count, 1 WG/CU -> co-resident in practice)
        rnn_persistent<<<dim3(NWG), dim3(256), SMEM, stream>>>(
            x, W1h, W1f, b1, b1f, Wl0p, bP0, Wl1p, bP1, W2h, b2,
            act0, act1, c0, c1, out, arrive, release);
    }
}

// Round 6
// 7245.515 us; speedup vs baseline: 2.5880x; 1.3552x over previous
//
#include <hip/hip_runtime.h>

typedef _Float16 half_t;
typedef _Float16 half8 __attribute__((ext_vector_type(8)));
typedef float floatx4 __attribute__((ext_vector_type(4)));

#define NT   300
#define NB   256
#define DIN  512
#define DH   512
#define DOUT 128
#define DX   384        // IN - OUT
#define KZ   896        // folded z GEMM K: 384 (xh) + 512 (h1)
#define NG   2048       // 4*DH gate rows
#define NWG  256
#define SMEM 131072     // 64KB ih-slice + 64KB hh-slice per WG

#define WAITVM(N) do { asm volatile("s_waitcnt vmcnt(" #N ")" ::: "memory"); \
                       __builtin_amdgcn_sched_barrier(0); } while (0)

// ---------------------------------------------------------------------------
// helpers
// ---------------------------------------------------------------------------

__device__ __forceinline__ float sigm(float x)  { return __builtin_amdgcn_rcpf(1.f + __expf(-x)); }
__device__ __forceinline__ float tanhx(float x) { return 1.f - 2.f * __builtin_amdgcn_rcpf(__expf(2.f * x) + 1.f); }

__device__ __forceinline__ half8 cvt8(const float* s) {
    float4 f0 = *(const float4*)s, f1 = *(const float4*)(s + 4);
    half8 h;
    h[0] = (half_t)f0.x; h[1] = (half_t)f0.y; h[2] = (half_t)f0.z; h[3] = (half_t)f0.w;
    h[4] = (half_t)f1.x; h[5] = (half_t)f1.y; h[6] = (half_t)f1.z; h[7] = (half_t)f1.w;
    return h;
}

// coherent (LLC, sc0 sc1) batched loads — counted by caller via WAITVM
__device__ __forceinline__ void ldA8(const half_t* b, half8& r0, half8& r1, half8& r2, half8& r3,
                                     half8& r4, half8& r5, half8& r6, half8& r7) {
    asm volatile(
        "global_load_dwordx4 %0, %8, off sc0 sc1\n\t"
        "global_load_dwordx4 %1, %8, off offset:64 sc0 sc1\n\t"
        "global_load_dwordx4 %2, %8, off offset:128 sc0 sc1\n\t"
        "global_load_dwordx4 %3, %8, off offset:192 sc0 sc1\n\t"
        "global_load_dwordx4 %4, %8, off offset:256 sc0 sc1\n\t"
        "global_load_dwordx4 %5, %8, off offset:320 sc0 sc1\n\t"
        "global_load_dwordx4 %6, %8, off offset:384 sc0 sc1\n\t"
        "global_load_dwordx4 %7, %8, off offset:448 sc0 sc1"
        : "=&v"(r0), "=&v"(r1), "=&v"(r2), "=&v"(r3),
          "=&v"(r4), "=&v"(r5), "=&v"(r6), "=&v"(r7)
        : "v"(b) : "memory");
}
__device__ __forceinline__ void ldA4(const half_t* b, half8& r0, half8& r1, half8& r2, half8& r3) {
    asm volatile(
        "global_load_dwordx4 %0, %4, off sc0 sc1\n\t"
        "global_load_dwordx4 %1, %4, off offset:64 sc0 sc1\n\t"
        "global_load_dwordx4 %2, %4, off offset:128 sc0 sc1\n\t"
        "global_load_dwordx4 %3, %4, off offset:192 sc0 sc1"
        : "=&v"(r0), "=&v"(r1), "=&v"(r2), "=&v"(r3)
        : "v"(b) : "memory");
}
// cached (L1/L2) batched loads for read-only pre-pass outputs (W1f)
__device__ __forceinline__ void ldC8(const half_t* b, half8& r0, half8& r1, half8& r2, half8& r3,
                                     half8& r4, half8& r5, half8& r6, half8& r7) {
    asm volatile(
        "global_load_dwordx4 %0, %8, off\n\t"
        "global_load_dwordx4 %1, %8, off offset:64\n\t"
        "global_load_dwordx4 %2, %8, off offset:128\n\t"
        "global_load_dwordx4 %3, %8, off offset:192\n\t"
        "global_load_dwordx4 %4, %8, off offset:256\n\t"
        "global_load_dwordx4 %5, %8, off offset:320\n\t"
        "global_load_dwordx4 %6, %8, off offset:384\n\t"
        "global_load_dwordx4 %7, %8, off offset:448"
        : "=&v"(r0), "=&v"(r1), "=&v"(r2), "=&v"(r3),
          "=&v"(r4), "=&v"(r5), "=&v"(r6), "=&v"(r7)
        : "v"(b) : "memory");
}
__device__ __forceinline__ void ldC4(const half_t* b, half8& r0, half8& r1, half8& r2, half8& r3) {
    asm volatile(
        "global_load_dwordx4 %0, %4, off\n\t"
        "global_load_dwordx4 %1, %4, off offset:64\n\t"
        "global_load_dwordx4 %2, %4, off offset:128\n\t"
        "global_load_dwordx4 %3, %4, off offset:192"
        : "=&v"(r0), "=&v"(r1), "=&v"(r2), "=&v"(r3)
        : "v"(b) : "memory");
}

__device__ __forceinline__ void st_coh_h(half_t* p, float v) {
    union { half_t h; unsigned short u; } c; c.h = (half_t)v;
    unsigned w = c.u;
    asm volatile("global_store_short %0, %1, off sc0 sc1" :: "v"(p), "v"(w) : "memory");
}
__device__ __forceinline__ void st_coh_h8(half_t* p, half8 v) {
    asm volatile("global_store_dwordx4 %0, %1, off sc0 sc1" :: "v"(p), "v"(v) : "memory");
}
__device__ __forceinline__ unsigned ld_flag(const unsigned* p) {
    unsigned v;
    asm volatile("global_load_dword %0, %1, off sc0 sc1\n\ts_waitcnt vmcnt(0)"
                 : "=v"(v) : "v"(p) : "memory");
    return v;
}
__device__ __forceinline__ void st_flag(unsigned* p, unsigned v) {
    asm volatile("global_store_dword %0, %1, off sc0 sc1" :: "v"(p), "v"(v) : "memory");
}

// all-to-all barrier: WG w stores phase to slot w; thread i of EVERY WG polls
// slot i (blockDim == NWG == 256). No central WG, no release flag.
__device__ __forceinline__ void grid_barrier(unsigned* arrive, unsigned phase) {
    asm volatile("s_waitcnt vmcnt(0) lgkmcnt(0)" ::: "memory");   // drain own stores
    __syncthreads();
    if (threadIdx.x == 0) st_flag(arrive + (size_t)blockIdx.x * 16, phase);
    const unsigned* slot = arrive + (size_t)threadIdx.x * 16;
    while (ld_flag(slot) < phase) {}
    __syncthreads();
}

// ---------------------------------------------------------------------------
// pre-pass kernels (every call — no caching allowed)
// ---------------------------------------------------------------------------

__global__ void cvt_f32_f16(const float* __restrict__ src, half_t* __restrict__ dst, int n) {
    for (int i = blockIdx.x * blockDim.x + threadIdx.x; i < n; i += gridDim.x * blockDim.x)
        dst[i] = (half_t)src[i];
}

// W1f = [W1x | W1y@W2] (512 x 896) fp16 ; b1f = b1 + W1y@b2
__global__ void fold_w1(const float* __restrict__ w1, const float* __restrict__ w2,
                        const float* __restrict__ b1, const float* __restrict__ b2,
                        half_t* __restrict__ W1f, float* __restrict__ b1f) {
    __shared__ float wy[128], b2s[128];
    const int h = blockIdx.x, tid = threadIdx.x;
    if (tid < 128) { wy[tid] = w1[(size_t)h * DIN + DX + tid]; b2s[tid] = b2[tid]; }
    __syncthreads();
    for (int k = tid; k < DX; k += 256) W1f[(size_t)h * KZ + k] = (half_t)w1[(size_t)h * DIN + k];
    for (int d = tid; d < DH; d += 256) {
        float s = 0.f;
        for (int j = 0; j < 128; ++j) s += wy[j] * w2[(size_t)j * DH + d];
        W1f[(size_t)h * KZ + DX + d] = (half_t)s;
    }
    if (tid == 0) {
        float s = 0.f;
        for (int j = 0; j < 128; ++j) s += wy[j] * b2s[j];
        b1f[h] = b1[h] + s;
    }
}

// Pack one 2048x512 gate matrix frag-major with gate interleave.
// packed col n = (d>>4)*64 + g*16 + (d&15); unit u = ((ct*16+kf)*4+cf)*64+lane
// holds half8 of B[k = kf*32+(lane>>4)*8 + j][n = ct*64+cf*16+(lane&15)].
__global__ void pack512(const float* __restrict__ w, half_t* __restrict__ Wp) {
    const int u = blockIdx.x * blockDim.x + threadIdx.x;   // 0..131071
    const int lane = u & 63;
    const int n = (u >> 12) * 64 + ((u >> 6) & 3) * 16 + (lane & 15);
    const int d = ((n >> 6) << 4) | (n & 15);
    const int g = (n >> 4) & 3;
    const int k0 = ((u >> 8) & 15) * 32 + (lane >> 4) * 8;
    const float* src = w + (size_t)(g * DH + d) * DH + k0;
    half8 v;
    #pragma unroll
    for (int j = 0; j < 8; ++j) v[j] = (half_t)src[j];
    *(half8*)&Wp[(size_t)u * 8] = v;
}

__global__ void pack_bias(const float* __restrict__ bih, const float* __restrict__ bhh,
                          float* __restrict__ bP) {
    const int n = blockIdx.x * blockDim.x + threadIdx.x;   // 0..2047
    const int d = ((n >> 6) << 4) | (n & 15);
    const int g = (n >> 4) & 3;
    bP[n] = bih[g * DH + d] + bhh[g * DH + d];
}

__global__ void init_all(float* c0, float* c1, unsigned* arrive) {
    const int step = gridDim.x * blockDim.x;
    const int i0 = blockIdx.x * blockDim.x + threadIdx.x;
    for (int k = i0; k < NB * DH; k += step) { c0[k] = 0.f; c1[k] = 0.f; }
    for (int k = i0; k < NWG * 16; k += step) arrive[k] = 0u;
}

// ---------------------------------------------------------------------------
// persistent kernel: 256 WGs x 256 thr.
// grp0 (WG 0..127): layer-0 weights LDS-stationary (64-col slice, ih+hh).
// grp1 (WG 128..255): layer-1 weights. Per step t (3 phases, all-WG barrier each):
//   PH_a: grp0 L0z(t) [+carried L0h acc] -> h0(t) ; grp1 acc1 = L1h(t)
//   PH_b: grp1 L1z(t) [+acc1]            -> h1(t) ; grp0 accC = L0h(t+1)
//   PH_c: grp1 Z(t+1) -> zbuf ; grp0: Y(t) (8 WGs) + x(t+2) fp16 convert (120 WGs)
// ---------------------------------------------------------------------------

__device__ __forceinline__ void gemm512(const half_t* __restrict__ Ab,
                                        const half_t* __restrict__ BstSeg,
                                        floatx4 acc[4], int lane) {
    half8 p[8], q[8];
    ldA8(Ab,       p[0], p[1], p[2], p[3], p[4], p[5], p[6], p[7]);
    ldA8(Ab + 256, q[0], q[1], q[2], q[3], q[4], q[5], q[6], q[7]);
    WAITVM(8);
    #pragma unroll
    for (int j = 0; j < 8; ++j)
        #pragma unroll
        for (int cf = 0; cf < 4; ++cf)
            acc[cf] = __builtin_amdgcn_mfma_f32_16x16x32_f16(
                p[j], *(const half8*)&BstSeg[(size_t)((j * 4 + cf) * 64 + lane) * 8],
                acc[cf], 0, 0, 0);
    WAITVM(0);
    #pragma unroll
    for (int j = 0; j < 8; ++j)
        #pragma unroll
        for (int cf = 0; cf < 4; ++cf)
            acc[cf] = __builtin_amdgcn_mfma_f32_16x16x32_f16(
                q[j], *(const half8*)&BstSeg[(size_t)(((j + 8) * 4 + cf) * 64 + lane) * 8],
                acc[cf], 0, 0, 0);
}

__device__ __forceinline__ void lstm_epi(floatx4 acc[4], const float* __restrict__ bP,
                                         float* __restrict__ cb, half_t* __restrict__ hdst,
                                         int ct, int wrow, int lane) {
    const int l15 = lane & 15, l4 = lane >> 4;
    const int d = ct * 16 + l15;
    const float bi = bP[ct * 64 + l15], bf_ = bP[ct * 64 + 16 + l15];
    const float bg = bP[ct * 64 + 32 + l15], bo = bP[ct * 64 + 48 + l15];
    #pragma unroll
    for (int r = 0; r < 4; ++r) {
        const int m = wrow + l4 * 4 + r;
        const float gi = acc[0][r] + bi, gf = acc[1][r] + bf_;
        const float gg = acc[2][r] + bg, go = acc[3][r] + bo;
        const float si = sigm(gi), sf = sigm(gf), so = sigm(go);
        const float cn = sf * cb[(size_t)m * DH + d] + si * tanhx(gg);
        const float hn = so * tanhx(cn);
        cb[(size_t)m * DH + d] = cn;            // WG-private, cached path
        st_coh_h(&hdst[(size_t)m * DH + d], hn);
    }
}

__global__ void __launch_bounds__(256, 1) rnn_persistent(
        const float* __restrict__ x, const half_t* __restrict__ W1h,
        const half_t* __restrict__ W1f, const float* __restrict__ b1,
        const float* __restrict__ b1f, const half_t* __restrict__ Wl0p,
        const float* __restrict__ bP0, const half_t* __restrict__ Wl1p,
        const float* __restrict__ bP1, const half_t* __restrict__ W2h,
        const float* __restrict__ b2, half_t* __restrict__ zbuf,
        half_t* __restrict__ h0buf, half_t* __restrict__ h1buf,
        half_t* __restrict__ xhst, float* __restrict__ c0,
        float* __restrict__ c1, float* __restrict__ out,
        unsigned* __restrict__ arrive)
{
    extern __shared__ __align__(16) char smem[];
    half_t* Bst = (half_t*)smem;                 // [0,64KB) = ih slice, [64KB,128KB) = hh
    const int tid = threadIdx.x;
    const int wg = blockIdx.x;
    const int lane = tid & 63, wid = tid >> 6;
    const int l15 = lane & 15, l4 = lane >> 4;
    const int grp = wg >> 7, lwg = wg & 127;
    const int ct = lwg >> 2, rt = lwg & 3;
    const int wrow = rt * 64 + wid * 16;
    const floatx4 z4 = {0.f, 0.f, 0.f, 0.f};

    // stationary weight slices: 64 cols x 512 K x {ih, hh}
    {
        const half_t* wsrc = grp ? Wl1p : Wl0p;
        for (int i = tid; i < 8192; i += 256) {
            size_t srcoff = (i < 4096)
                ? ((size_t)ct * 32768 + (size_t)i * 8)
                : (1048576 + (size_t)ct * 32768 + (size_t)(i - 4096) * 8);
            *(half8*)&Bst[(size_t)i * 8] = *(const half8*)&wsrc[srcoff];
        }
    }
    __syncthreads();

    const size_t aoffL = (size_t)(wrow + l15) * DH + l4 * 8;   // lstm A fragment base

    // ---- PH_0: grp1 computes z(0) from f32 x(0); grp0 converts xh(1) ----
    if (grp == 1) {
        const int zc = lwg >> 2, zr = lwg & 3;
        const int zrow = zr * 64 + wid * 16;
        const int arow = zrow + l15;
        const int n = zc * 16 + l15;
        floatx4 acc = z4;
        #pragma unroll 4
        for (int kf = 0; kf < 16; ++kf) {
            half8 a = cvt8(x + (size_t)arow * DIN + kf * 32 + l4 * 8);
            half8 b = *(const half8*)&W1h[(size_t)n * DH + kf * 32 + l4 * 8];
            acc = __builtin_amdgcn_mfma_f32_16x16x32_f16(a, b, acc, 0, 0, 0);
        }
        const float bb = b1[n];
        #pragma unroll
        for (int r = 0; r < 4; ++r)
            st_coh_h(&zbuf[(size_t)(zrow + l4 * 4 + r) * DH + n], fmaxf(acc[r] + bb, 0.f));
    } else {
        const float* xs = x + (size_t)1 * NB * DIN;
        half_t* xd = xhst + (size_t)1 * NB * DIN;    // slot 1
        for (int u = lwg * 256 + tid; u < NB * DIN / 8; u += 128 * 256)
            st_coh_h8(xd + (size_t)u * 8, cvt8(xs + (size_t)u * 8));
    }
    unsigned ph = 1;
    grid_barrier(arrive, ph);

    floatx4 accC[4] = {z4, z4, z4, z4};   // grp0: carried L0h partial (h0(-1)=0)
    floatx4 acc1[4] = {z4, z4, z4, z4};   // grp1: L1h partial (PH_a -> PH_b)

    for (int t = 0; t < NT; ++t) {
        const int p = t & 1;
        half_t* z_t  = zbuf  + (size_t)p * (NB * DH);
        half_t* h0_t = h0buf + (size_t)p * (NB * DH);
        half_t* h1_t = h1buf + (size_t)p * (NB * DH);
        half_t* h1_p = h1buf + (size_t)(p ^ 1) * (NB * DH);   // h1(t-1)

        // ---- PH_a ----
        if (grp == 0) {
            gemm512(z_t + aoffL, Bst, accC, lane);             // + z(t) @ W0ih
            lstm_epi(accC, bP0, c0, h0_t, ct, wrow, lane);     // -> c0, h0(t)
        } else {
            acc1[0] = z4; acc1[1] = z4; acc1[2] = z4; acc1[3] = z4;
            if (t > 0)
                gemm512(h1_p + aoffL, Bst + 32768, acc1, lane); // h1(t-1) @ W1hh
        }
        grid_barrier(arrive, ++ph);

        // ---- PH_b ----
        if (grp == 1) {
            gemm512(h0_t + aoffL, Bst, acc1, lane);            // + h0(t) @ W1ih
            lstm_epi(acc1, bP1, c1, h1_t, ct, wrow, lane);     // -> c1, h1(t)
        } else {
            accC[0] = z4; accC[1] = z4; accC[2] = z4; accC[3] = z4;
            if (t + 1 < NT)
                gemm512(h0_t + aoffL, Bst + 32768, accC, lane); // h0(t) @ W0hh
        }
        grid_barrier(arrive, ++ph);

        // ---- PH_c ----
        if (grp == 1) {
            if (t + 1 < NT) {   // Z(t+1) = relu(xh(t+1)@W1x + h1(t)@Wc + b1f)
                const int zc = lwg >> 2, zr = lwg & 3;
                const int zrow = zr * 64 + wid * 16;
                const int arow = zrow + l15;
                const int n = zc * 16 + l15;
                const half_t* xh_n = xhst + (size_t)((t + 1) & 1) * (NB * DIN);
                half_t* z_n = zbuf + (size_t)((t + 1) & 1) * (NB * DH);
                const half_t* xb = xh_n + (size_t)arow * DIN + l4 * 8;
                const half_t* hb = h1_t + (size_t)arow * DH + l4 * 8;
                const half_t* wb = W1f + (size_t)n * KZ + l4 * 8;
                half8 xf[12], bx[12], hf[16], bh[16];
                ldA8(xb, xf[0], xf[1], xf[2], xf[3], xf[4], xf[5], xf[6], xf[7]);
                ldA4(xb + 256, xf[8], xf[9], xf[10], xf[11]);
                ldC8(wb, bx[0], bx[1], bx[2], bx[3], bx[4], bx[5], bx[6], bx[7]);
                ldC4(wb + 256, bx[8], bx[9], bx[10], bx[11]);
                WAITVM(0);
                ldA8(hb,       hf[0], hf[1], hf[2], hf[3], hf[4], hf[5], hf[6], hf[7]);
                ldA8(hb + 256, hf[8], hf[9], hf[10], hf[11], hf[12], hf[13], hf[14], hf[15]);
                ldC8(wb + 384,       bh[0], bh[1], bh[2], bh[3], bh[4], bh[5], bh[6], bh[7]);
                ldC8(wb + 384 + 256, bh[8], bh[9], bh[10], bh[11], bh[12], bh[13], bh[14], bh[15]);
                floatx4 acc = z4;
                #pragma unroll
                for (int j = 0; j < 12; ++j)
                    acc = __builtin_amdgcn_mfma_f32_16x16x32_f16(xf[j], bx[j], acc, 0, 0, 0);
                WAITVM(0);
                #pragma unroll
                for (int j = 0; j < 16; ++j)
                    acc = __builtin_amdgcn_mfma_f32_16x16x32_f16(hf[j], bh[j], acc, 0, 0, 0);
                const float bb = b1f[n];
                #pragma unroll
                for (int r = 0; r < 4; ++r)
                    st_coh_h(&z_n[(size_t)(zrow + l4 * 4 + r) * DH + n], fmaxf(acc[r] + bb, 0.f));
            }
        } else if (lwg < 8) {   // Y(t) = h1(t) @ W2^T + b2 -> out[t]
            const int row0 = lwg * 32;
            const int wr = wid >> 1, wc = wid & 1;
            const int arow = row0 + wr * 16 + l15;
            const half_t* hb = h1_t + (size_t)arow * DH + l4 * 8;
            half8 pA[8], qA[8];
            ldA8(hb,       pA[0], pA[1], pA[2], pA[3], pA[4], pA[5], pA[6], pA[7]);
            ldA8(hb + 256, qA[0], qA[1], qA[2], qA[3], qA[4], qA[5], qA[6], qA[7]);
            floatx4 acc[4] = {z4, z4, z4, z4};
            WAITVM(0);
            #pragma unroll
            for (int j = 0; j < 16; ++j) {
                half8 a = (j < 8) ? pA[j & 7] : qA[j & 7];
                #pragma unroll
                for (int cf = 0; cf < 4; ++cf) {
                    const int n = wc * 64 + cf * 16 + l15;
                    half8 b = *(const half8*)&W2h[(size_t)n * DH + j * 32 + l4 * 8];
                    acc[cf] = __builtin_amdgcn_mfma_f32_16x16x32_f16(a, b, acc[cf], 0, 0, 0);
                }
            }
            float* yo = out + (size_t)t * NB * DOUT;
            #pragma unroll
            for (int cf = 0; cf < 4; ++cf) {
                const int n = wc * 64 + cf * 16 + l15;
                const float bb = b2[n];
                #pragma unroll
                for (int r = 0; r < 4; ++r)
                    yo[(size_t)(row0 + wr * 16 + l4 * 4 + r) * DOUT + n] = acc[cf][r] + bb;
            }
        } else if (t + 2 < NT) {   // convert x(t+2) -> xh slot (t+2)&1
            const float* xs = x + (size_t)(t + 2) * NB * DIN;
            half_t* xd = xhst + (size_t)((t + 2) & 1) * (NB * DIN);
            for (int u = (lwg - 8) * 256 + tid; u < NB * DIN / 8; u += 120 * 256)
                st_coh_h8(xd + (size_t)u * 8, cvt8(xs + (size_t)u * 8));
        }
        if (t < NT - 1) grid_barrier(arrive, ++ph);
    }
}

// ---------------------------------------------------------------------------

extern "C" void kernel_launch(void* const* d_in, const int* in_sizes, int n_in,
                              void* d_out, int out_size, void* d_ws, size_t ws_size,
                              hipStream_t stream) {
    const float* x    = (const float*)d_in[0];
    const float* w1   = (const float*)d_in[1];
    const float* b1   = (const float*)d_in[2];
    const float* w_ih = (const float*)d_in[3];
    const float* w_hh = (const float*)d_in[4];
    const float* b_ih = (const float*)d_in[5];
    const float* b_hh = (const float*)d_in[6];
    const float* w2   = (const float*)d_in[7];
    const float* b2   = (const float*)d_in[8];
    float* out = (float*)d_out;
    (void)in_sizes; (void)n_in; (void)out_size; (void)ws_size;

    char* ws = (char*)d_ws;
    size_t off = 0;
    auto take = [&](size_t bytes) -> char* {
        char* p = ws + off;
        off += (bytes + 255) & ~(size_t)255;
        return p;
    };
    half_t* W1h  = (half_t*)take((size_t)512 * 512 * 2);
    half_t* W2h  = (half_t*)take((size_t)128 * 512 * 2);
    half_t* W1f  = (half_t*)take((size_t)512 * KZ * 2);
    half_t* Wl0p = (half_t*)take((size_t)NG * 1024 * 2);   // [ih 2MB | hh 2MB]
    half_t* Wl1p = (half_t*)take((size_t)NG * 1024 * 2);
    float*  b1f  = (float*)take((size_t)512 * 4);
    float*  bP0  = (float*)take((size_t)NG * 4);
    float*  bP1  = (float*)take((size_t)NG * 4);
    float*  c0   = (float*)take((size_t)NB * DH * 4);
    float*  c1   = (float*)take((size_t)NB * DH * 4);
    half_t* zbuf  = (half_t*)take((size_t)2 * NB * DH * 2);
    half_t* h0buf = (half_t*)take((size_t)2 * NB * DH * 2);
    half_t* h1buf = (half_t*)take((size_t)2 * NB * DH * 2);
    half_t* xhst  = (half_t*)take((size_t)2 * NB * DIN * 2);
    unsigned* arrive = (unsigned*)take((size_t)NWG * 16 * 4);

    cvt_f32_f16<<<256, 256, 0, stream>>>(w1, W1h, 512 * 512);
    cvt_f32_f16<<<64, 256, 0, stream>>>(w2, W2h, 128 * 512);
    fold_w1<<<512, 256, 0, stream>>>(w1, w2, b1, b2, W1f, b1f);
    pack512<<<512, 256, 0, stream>>>(w_ih, Wl0p);
    pack512<<<512, 256, 0, stream>>>(w_hh, Wl0p + 1048576);
    pack512<<<512, 256, 0, stream>>>(w_ih + (size_t)NG * DH, Wl1p);
    pack512<<<512, 256, 0, stream>>>(w_hh + (size_t)NG * DH, Wl1p + 1048576);
    pack_bias<<<8, 256, 0, stream>>>(b_ih, b_hh, bP0);
    pack_bias<<<8, 256, 0, stream>>>(b_ih + NG, b_hh + NG, bP1);
    init_all<<<256, 256, 0, stream>>>(c0, c1, arrive);

    hipFuncSetAttribute((const void*)rnn_persistent,
                        hipFuncAttributeMaxDynamicSharedMemorySize, SMEM);

    void* args[] = { (void*)&x, (void*)&W1h, (void*)&W1f, (void*)&b1, (void*)&b1f,
                     (void*)&Wl0p, (void*)&bP0, (void*)&Wl1p, (void*)&bP1,
                     (void*)&W2h, (void*)&b2, (void*)&zbuf, (void*)&h0buf,
                     (void*)&h1buf, (void*)&xhst, (void*)&c0, (void*)&c1,
                     (void*)&out, (void*)&arrive };
    hipError_t e = hipLaunchCooperativeKernel((void*)rnn_persistent, dim3(NWG), dim3(256),
                                              args, SMEM, stream);
    if (e != hipSuccess) {
        rnn_persistent<<<dim3(NWG), dim3(256), SMEM, stream>>>(
            x, W1h, W1f, b1, b1f, Wl0p, bP0, Wl1p, bP1, W2h, b2,
            zbuf, h0buf, h1buf, xhst, c0, c1, out, arrive);
    }
}

// Round 7
// 5766.140 us; speedup vs baseline: 3.2520x; 1.2566x over previous
//
#include <hip/hip_runtime.h>

typedef _Float16 half_t;
typedef _Float16 half8 __attribute__((ext_vector_type(8)));
typedef float floatx4 __attribute__((ext_vector_type(4)));

#define NT   300
#define NB   256
#define DIN  512
#define DH   512
#define DOUT 128
#define DX   384        // IN - OUT
#define KZ   896        // folded z GEMM K: 384 (xh) + 512 (h1)
#define NG   2048       // 4*DH gate rows
#define NWG  256
#define SMEM 131072     // 64KB ih-slice + 64KB hh-slice per WG

#define WAITVM(N) do { asm volatile("s_waitcnt vmcnt(" #N ")" ::: "memory"); \
                       __builtin_amdgcn_sched_barrier(0); } while (0)

// ---------------------------------------------------------------------------
// helpers
// ---------------------------------------------------------------------------

__device__ __forceinline__ float sigm(float x)  { return __builtin_amdgcn_rcpf(1.f + __expf(-x)); }
__device__ __forceinline__ float tanhx(float x) { return 1.f - 2.f * __builtin_amdgcn_rcpf(__expf(2.f * x) + 1.f); }

__device__ __forceinline__ half8 cvt8(const float* s) {
    float4 f0 = *(const float4*)s, f1 = *(const float4*)(s + 4);
    half8 h;
    h[0] = (half_t)f0.x; h[1] = (half_t)f0.y; h[2] = (half_t)f0.z; h[3] = (half_t)f0.w;
    h[4] = (half_t)f1.x; h[5] = (half_t)f1.y; h[6] = (half_t)f1.z; h[7] = (half_t)f1.w;
    return h;
}

// coherent (LLC, sc0 sc1) batched loads — counted by caller via WAITVM
__device__ __forceinline__ void ldA8(const half_t* b, half8& r0, half8& r1, half8& r2, half8& r3,
                                     half8& r4, half8& r5, half8& r6, half8& r7) {
    asm volatile(
        "global_load_dwordx4 %0, %8, off sc0 sc1\n\t"
        "global_load_dwordx4 %1, %8, off offset:64 sc0 sc1\n\t"
        "global_load_dwordx4 %2, %8, off offset:128 sc0 sc1\n\t"
        "global_load_dwordx4 %3, %8, off offset:192 sc0 sc1\n\t"
        "global_load_dwordx4 %4, %8, off offset:256 sc0 sc1\n\t"
        "global_load_dwordx4 %5, %8, off offset:320 sc0 sc1\n\t"
        "global_load_dwordx4 %6, %8, off offset:384 sc0 sc1\n\t"
        "global_load_dwordx4 %7, %8, off offset:448 sc0 sc1"
        : "=&v"(r0), "=&v"(r1), "=&v"(r2), "=&v"(r3),
          "=&v"(r4), "=&v"(r5), "=&v"(r6), "=&v"(r7)
        : "v"(b) : "memory");
}
__device__ __forceinline__ void ldA4(const half_t* b, half8& r0, half8& r1, half8& r2, half8& r3) {
    asm volatile(
        "global_load_dwordx4 %0, %4, off sc0 sc1\n\t"
        "global_load_dwordx4 %1, %4, off offset:64 sc0 sc1\n\t"
        "global_load_dwordx4 %2, %4, off offset:128 sc0 sc1\n\t"
        "global_load_dwordx4 %3, %4, off offset:192 sc0 sc1"
        : "=&v"(r0), "=&v"(r1), "=&v"(r2), "=&v"(r3)
        : "v"(b) : "memory");
}
// cached (L1/L2) batched loads for read-only pre-pass outputs (W1f)
__device__ __forceinline__ void ldC8(const half_t* b, half8& r0, half8& r1, half8& r2, half8& r3,
                                     half8& r4, half8& r5, half8& r6, half8& r7) {
    asm volatile(
        "global_load_dwordx4 %0, %8, off\n\t"
        "global_load_dwordx4 %1, %8, off offset:64\n\t"
        "global_load_dwordx4 %2, %8, off offset:128\n\t"
        "global_load_dwordx4 %3, %8, off offset:192\n\t"
        "global_load_dwordx4 %4, %8, off offset:256\n\t"
        "global_load_dwordx4 %5, %8, off offset:320\n\t"
        "global_load_dwordx4 %6, %8, off offset:384\n\t"
        "global_load_dwordx4 %7, %8, off offset:448"
        : "=&v"(r0), "=&v"(r1), "=&v"(r2), "=&v"(r3),
          "=&v"(r4), "=&v"(r5), "=&v"(r6), "=&v"(r7)
        : "v"(b) : "memory");
}
__device__ __forceinline__ void ldC4(const half_t* b, half8& r0, half8& r1, half8& r2, half8& r3) {
    asm volatile(
        "global_load_dwordx4 %0, %4, off\n\t"
        "global_load_dwordx4 %1, %4, off offset:64\n\t"
        "global_load_dwordx4 %2, %4, off offset:128\n\t"
        "global_load_dwordx4 %3, %4, off offset:192"
        : "=&v"(r0), "=&v"(r1), "=&v"(r2), "=&v"(r3)
        : "v"(b) : "memory");
}

__device__ __forceinline__ void st_coh_u64(half_t* p, unsigned long long v) {
    asm volatile("global_store_dwordx2 %0, %1, off sc0 sc1" :: "v"(p), "v"(v) : "memory");
}
__device__ __forceinline__ void st_coh_h8(half_t* p, half8 v) {
    asm volatile("global_store_dwordx4 %0, %1, off sc0 sc1" :: "v"(p), "v"(v) : "memory");
}
__device__ __forceinline__ unsigned ld_flag(const unsigned* p) {
    unsigned v;
    asm volatile("global_load_dword %0, %1, off sc0 sc1\n\ts_waitcnt vmcnt(0)"
                 : "=v"(v) : "v"(p) : "memory");
    return v;
}
__device__ __forceinline__ void st_flag(unsigned* p, unsigned v) {
    asm volatile("global_store_dword %0, %1, off sc0 sc1" :: "v"(p), "v"(v) : "memory");
}

// producer-group semaphore: producer WG signals its own slot (after drain);
// consumers poll all producer slots in parallel (thread i polls slot i).
__device__ __forceinline__ void signal_slot(unsigned* sem, int slot, unsigned value) {
    asm volatile("s_waitcnt vmcnt(0) lgkmcnt(0)" ::: "memory");   // own data at LLC
    __syncthreads();
    if (threadIdx.x == 0) st_flag(sem + (size_t)slot * 16, value);
}
__device__ __forceinline__ void wait_slots(const unsigned* sem, int nslots, unsigned target) {
    if ((int)threadIdx.x < nslots) {
        const unsigned* slot = sem + (size_t)threadIdx.x * 16;
        while (ld_flag(slot) < target) {}
    }
    __syncthreads();
}

// ---------------------------------------------------------------------------
// pre-pass kernels (every call — no caching allowed)
// ---------------------------------------------------------------------------

__global__ void cvt_f32_f16(const float* __restrict__ src, half_t* __restrict__ dst, int n) {
    for (int i = blockIdx.x * blockDim.x + threadIdx.x; i < n; i += gridDim.x * blockDim.x)
        dst[i] = (half_t)src[i];
}

// W1f = [W1x | W1y@W2] (512 x 896) fp16 ; b1f = b1 + W1y@b2
__global__ void fold_w1(const float* __restrict__ w1, const float* __restrict__ w2,
                        const float* __restrict__ b1, const float* __restrict__ b2,
                        half_t* __restrict__ W1f, float* __restrict__ b1f) {
    __shared__ float wy[128], b2s[128];
    const int h = blockIdx.x, tid = threadIdx.x;
    if (tid < 128) { wy[tid] = w1[(size_t)h * DIN + DX + tid]; b2s[tid] = b2[tid]; }
    __syncthreads();
    for (int k = tid; k < DX; k += 256) W1f[(size_t)h * KZ + k] = (half_t)w1[(size_t)h * DIN + k];
    for (int d = tid; d < DH; d += 256) {
        float s = 0.f;
        for (int j = 0; j < 128; ++j) s += wy[j] * w2[(size_t)j * DH + d];
        W1f[(size_t)h * KZ + DX + d] = (half_t)s;
    }
    if (tid == 0) {
        float s = 0.f;
        for (int j = 0; j < 128; ++j) s += wy[j] * b2s[j];
        b1f[h] = b1[h] + s;
    }
}

// Pack one 2048x512 gate matrix frag-major with gate interleave.
__global__ void pack512(const float* __restrict__ w, half_t* __restrict__ Wp) {
    const int u = blockIdx.x * blockDim.x + threadIdx.x;   // 0..131071
    const int lane = u & 63;
    const int n = (u >> 12) * 64 + ((u >> 6) & 3) * 16 + (lane & 15);
    const int d = ((n >> 6) << 4) | (n & 15);
    const int g = (n >> 4) & 3;
    const int k0 = ((u >> 8) & 15) * 32 + (lane >> 4) * 8;
    const float* src = w + (size_t)(g * DH + d) * DH + k0;
    half8 v;
    #pragma unroll
    for (int j = 0; j < 8; ++j) v[j] = (half_t)src[j];
    *(half8*)&Wp[(size_t)u * 8] = v;
}

__global__ void pack_bias(const float* __restrict__ bih, const float* __restrict__ bhh,
                          float* __restrict__ bP) {
    const int n = blockIdx.x * blockDim.x + threadIdx.x;   // 0..2047
    const int d = ((n >> 6) << 4) | (n & 15);
    const int g = (n >> 4) & 3;
    bP[n] = bih[g * DH + d] + bhh[g * DH + d];
}

__global__ void init_all(unsigned* sems, int n) {
    for (int k = blockIdx.x * blockDim.x + threadIdx.x; k < n; k += gridDim.x * blockDim.x)
        sems[k] = 0u;
}

// ---------------------------------------------------------------------------
// persistent kernel: 256 WGs x 256 thr, skewed producer/consumer pipeline.
// grp0 (WG 0..127): layer-0; grp1 (WG 128..255): layer-1 + z + y handled below.
// Critical path/step: z(t)[grp1] -> h0(t)[grp0] -> h1(t)[grp1] -> z(t+1).
// Off-path: L0hh/L1hh partials (carried in regs), y(t) (8 grp0 WGs),
//           x(t+2) fp16 convert (120 grp0 WGs). Cell state c lives in VGPRs.
// ---------------------------------------------------------------------------

__device__ __forceinline__ void gemm512(const half_t* __restrict__ Ab,
                                        const half_t* __restrict__ BstSeg,
                                        floatx4 acc[4], int lane) {
    half8 p[8], q[8];
    ldA8(Ab,       p[0], p[1], p[2], p[3], p[4], p[5], p[6], p[7]);
    ldA8(Ab + 256, q[0], q[1], q[2], q[3], q[4], q[5], q[6], q[7]);
    WAITVM(8);
    #pragma unroll
    for (int j = 0; j < 8; ++j)
        #pragma unroll
        for (int cf = 0; cf < 4; ++cf)
            acc[cf] = __builtin_amdgcn_mfma_f32_16x16x32_f16(
                p[j], *(const half8*)&BstSeg[(size_t)((j * 4 + cf) * 64 + lane) * 8],
                acc[cf], 0, 0, 0);
    WAITVM(0);
    #pragma unroll
    for (int j = 0; j < 8; ++j)
        #pragma unroll
        for (int cf = 0; cf < 4; ++cf)
            acc[cf] = __builtin_amdgcn_mfma_f32_16x16x32_f16(
                q[j], *(const half8*)&BstSeg[(size_t)(((j + 8) * 4 + cf) * 64 + lane) * 8],
                acc[cf], 0, 0, 0);
}

__global__ void __launch_bounds__(256, 1) rnn_persistent(
        const float* __restrict__ x, const half_t* __restrict__ W1h,
        const half_t* __restrict__ W1f, const float* __restrict__ b1,
        const float* __restrict__ b1f, const half_t* __restrict__ Wl0p,
        const float* __restrict__ bP0, const half_t* __restrict__ Wl1p,
        const float* __restrict__ bP1, const half_t* __restrict__ W2h,
        const float* __restrict__ b2, half_t* __restrict__ zbuf,
        half_t* __restrict__ h0buf, half_t* __restrict__ h1buf,
        half_t* __restrict__ xhst, float* __restrict__ out,
        unsigned* __restrict__ semz, unsigned* __restrict__ semh0,
        unsigned* __restrict__ semh1, unsigned* __restrict__ semxh)
{
    extern __shared__ __align__(16) char smem[];
    half_t* Bst = (half_t*)smem;                 // [0,64KB) ih slice, [64KB,128KB) hh
    __shared__ __align__(16) half_t bounce[64 * 20];   // padded 64x16 store-coalescing tile
    const int tid = threadIdx.x;
    const int wg = blockIdx.x;
    const int lane = tid & 63, wid = tid >> 6;
    const int l15 = lane & 15, l4 = lane >> 4;
    const int grp = wg >> 7, lwg = wg & 127;
    const int ct = lwg >> 2, rt = lwg & 3;
    const int wrow = rt * 64 + wid * 16;
    const floatx4 z4 = {0.f, 0.f, 0.f, 0.f};

    // stationary weight slices: 64 packed cols x 512 K x {ih, hh}
    {
        const half_t* wsrc = grp ? Wl1p : Wl0p;
        for (int i = tid; i < 8192; i += 256) {
            size_t srcoff = (i < 4096)
                ? ((size_t)ct * 32768 + (size_t)i * 8)
                : (1048576 + (size_t)ct * 32768 + (size_t)(i - 4096) * 8);
            *(half8*)&Bst[(size_t)i * 8] = *(const half8*)&wsrc[srcoff];
        }
    }
    __syncthreads();

    const size_t aoffL = (size_t)(wrow + l15) * DH + l4 * 8;

    // epilogue store coalescer: tile rows rt*64.., cols colbase..+16
    auto bounce_out = [&](const float hv[4], half_t* dstbase) {
        #pragma unroll
        for (int r = 0; r < 4; ++r)
            bounce[(wid * 16 + l4 * 4 + r) * 20 + l15] = (half_t)hv[r];
        __syncthreads();
        const int row = tid >> 2, dq = tid & 3;
        unsigned long long v = *(const unsigned long long*)&bounce[row * 20 + dq * 4];
        st_coh_u64(dstbase + (size_t)row * DH + dq * 4, v);
    };

    float creg[4] = {0.f, 0.f, 0.f, 0.f};       // register-resident cell state

    // ---- prologue ----
    if (grp == 1) {
        // z(0) = relu(x[0] @ W1^T + b1), f32 A, full K=512 (fb(0)==x[0][:,384:])
        const int zc = lwg >> 2, zr = lwg & 3;
        const int zrow = zr * 64 + wid * 16;
        const int arow = zrow + l15;
        const int n = zc * 16 + l15;
        floatx4 acc = z4;
        #pragma unroll 4
        for (int kf = 0; kf < 16; ++kf) {
            half8 a = cvt8(x + (size_t)arow * DIN + kf * 32 + l4 * 8);
            half8 b = *(const half8*)&W1h[(size_t)n * DIN + kf * 32 + l4 * 8];
            acc = __builtin_amdgcn_mfma_f32_16x16x32_f16(a, b, acc, 0, 0, 0);
        }
        const float bb = b1[n];
        float zv[4];
        #pragma unroll
        for (int r = 0; r < 4; ++r) zv[r] = fmaxf(acc[r] + bb, 0.f);
        bounce_out(zv, zbuf + (size_t)(zr * 64) * DH + zc * 16);
        signal_slot(semz, lwg, 1u);
    } else if (lwg >= 8) {
        // convert x(1) -> xh slot 1
        const float* xs = x + (size_t)1 * NB * DIN;
        half_t* xd = xhst + (size_t)1 * NB * DIN;
        for (int u = (lwg - 8) * 256 + tid; u < NB * DIN / 8; u += 120 * 256)
            st_coh_h8(xd + (size_t)u * 8, cvt8(xs + (size_t)u * 8));
        signal_slot(semxh, lwg - 8, 1u);
    }

    if (grp == 0) {
        floatx4 accC[4] = {z4, z4, z4, z4};      // carried L0hh partial (h0(-1)=0)
        for (int t = 0; t < NT; ++t) {
            const int p = t & 1;
            half_t* z_t  = zbuf  + (size_t)p * (NB * DH);
            half_t* h0_t = h0buf + (size_t)p * (NB * DH);
            half_t* h1_t = h1buf + (size_t)p * (NB * DH);

            wait_slots(semz, 128, (unsigned)(t + 1));
            gemm512(z_t + aoffL, Bst, accC, lane);           // + z(t) @ W0ih
            {   // LSTM epilogue, c in regs
                const float bi = bP0[ct * 64 + l15], bf_ = bP0[ct * 64 + 16 + l15];
                const float bg = bP0[ct * 64 + 32 + l15], bo = bP0[ct * 64 + 48 + l15];
                float hv[4];
                #pragma unroll
                for (int r = 0; r < 4; ++r) {
                    const float gi = accC[0][r] + bi, gf = accC[1][r] + bf_;
                    const float gg = accC[2][r] + bg, go = accC[3][r] + bo;
                    const float si = sigm(gi), sf = sigm(gf), so = sigm(go);
                    const float cn = sf * creg[r] + si * tanhx(gg);
                    creg[r] = cn;
                    hv[r] = so * tanhx(cn);
                }
                bounce_out(hv, h0_t + (size_t)(rt * 64) * DH + ct * 16);
            }
            signal_slot(semh0, lwg, (unsigned)(t + 1));

            accC[0] = z4; accC[1] = z4; accC[2] = z4; accC[3] = z4;
            wait_slots(semh0, 128, (unsigned)(t + 1));       // all of h0(t) at LLC
            if (t + 1 < NT)
                gemm512(h0_t + aoffL, Bst + 32768, accC, lane);  // h0(t) @ W0hh

            if (lwg < 8) {
                // y(t) = h1(t) @ W2^T + b2
                wait_slots(semh1, 128, (unsigned)(t + 1));
                const int row0 = lwg * 32;
                const int wr = wid >> 1, wc = wid & 1;
                const int arow = row0 + wr * 16 + l15;
                const half_t* hb = h1_t + (size_t)arow * DH + l4 * 8;
                half8 pA[8], qA[8];
                ldA8(hb,       pA[0], pA[1], pA[2], pA[3], pA[4], pA[5], pA[6], pA[7]);
                ldA8(hb + 256, qA[0], qA[1], qA[2], qA[3], qA[4], qA[5], qA[6], qA[7]);
                floatx4 acc[4] = {z4, z4, z4, z4};
                WAITVM(0);
                #pragma unroll
                for (int j = 0; j < 16; ++j) {
                    half8 a = (j < 8) ? pA[j & 7] : qA[j & 7];
                    #pragma unroll
                    for (int cf = 0; cf < 4; ++cf) {
                        const int n = wc * 64 + cf * 16 + l15;
                        half8 b = *(const half8*)&W2h[(size_t)n * DH + j * 32 + l4 * 8];
                        acc[cf] = __builtin_amdgcn_mfma_f32_16x16x32_f16(a, b, acc[cf], 0, 0, 0);
                    }
                }
                float* yo = out + (size_t)t * NB * DOUT;
                #pragma unroll
                for (int cf = 0; cf < 4; ++cf) {
                    const int n = wc * 64 + cf * 16 + l15;
                    const float bb = b2[n];
                    #pragma unroll
                    for (int r = 0; r < 4; ++r)
                        yo[(size_t)(row0 + wr * 16 + l4 * 4 + r) * DOUT + n] = acc[cf][r] + bb;
                }
            } else if (t + 2 < NT) {
                // convert x(t+2) -> xh slot (t+2)&1  (readers of this slot are done:
                // we already waited semz >= t+1 which implies z(t) consumed xh(t))
                const float* xs = x + (size_t)(t + 2) * NB * DIN;
                half_t* xd = xhst + (size_t)((t + 2) & 1) * (NB * DIN);
                for (int u = (lwg - 8) * 256 + tid; u < NB * DIN / 8; u += 120 * 256)
                    st_coh_h8(xd + (size_t)u * 8, cvt8(xs + (size_t)u * 8));
                signal_slot(semxh, lwg - 8, (unsigned)(t + 2));
            }
        }
    } else {
        floatx4 acc1[4] = {z4, z4, z4, z4};
        const int zc = lwg >> 2, zr = lwg & 3;
        const int zrow = zr * 64 + wid * 16;
        const int zarow = zrow + l15;
        const int zn = zc * 16 + l15;
        for (int t = 0; t < NT; ++t) {
            const int p = t & 1;
            half_t* z_n  = zbuf  + (size_t)(p ^ 1) * (NB * DH);   // z(t+1) dest
            half_t* h0_t = h0buf + (size_t)p * (NB * DH);
            half_t* h1_t = h1buf + (size_t)p * (NB * DH);
            half_t* h1_p = h1buf + (size_t)(p ^ 1) * (NB * DH);   // h1(t-1)

            acc1[0] = z4; acc1[1] = z4; acc1[2] = z4; acc1[3] = z4;
            if (t > 0)
                gemm512(h1_p + aoffL, Bst + 32768, acc1, lane);   // h1(t-1) @ W1hh

            wait_slots(semh0, 128, (unsigned)(t + 1));
            gemm512(h0_t + aoffL, Bst, acc1, lane);               // + h0(t) @ W1ih
            {
                const float bi = bP1[ct * 64 + l15], bf_ = bP1[ct * 64 + 16 + l15];
                const float bg = bP1[ct * 64 + 32 + l15], bo = bP1[ct * 64 + 48 + l15];
                float hv[4];
                #pragma unroll
                for (int r = 0; r < 4; ++r) {
                    const float gi = acc1[0][r] + bi, gf = acc1[1][r] + bf_;
                    const float gg = acc1[2][r] + bg, go = acc1[3][r] + bo;
                    const float si = sigm(gi), sf = sigm(gf), so = sigm(go);
                    const float cn = sf * creg[r] + si * tanhx(gg);
                    creg[r] = cn;
                    hv[r] = so * tanhx(cn);
                }
                bounce_out(hv, h1_t + (size_t)(rt * 64) * DH + ct * 16);
            }
            signal_slot(semh1, lwg, (unsigned)(t + 1));

            if (t + 1 < NT) {
                // z(t+1) = relu(xh(t+1)@W1x + h1(t)@Wc + b1f); xh part first (off-path)
                wait_slots(semxh, 120, (unsigned)(t + 1));
                const half_t* xh_n = xhst + (size_t)((t + 1) & 1) * (NB * DIN);
                const half_t* xb = xh_n + (size_t)zarow * DIN + l4 * 8;
                const half_t* wb = W1f + (size_t)zn * KZ + l4 * 8;
                half8 xf[12], bx[12];
                ldA8(xb, xf[0], xf[1], xf[2], xf[3], xf[4], xf[5], xf[6], xf[7]);
                ldA4(xb + 256, xf[8], xf[9], xf[10], xf[11]);
                ldC8(wb, bx[0], bx[1], bx[2], bx[3], bx[4], bx[5], bx[6], bx[7]);
                ldC4(wb + 256, bx[8], bx[9], bx[10], bx[11]);
                WAITVM(0);
                floatx4 accZ = z4;
                #pragma unroll
                for (int j = 0; j < 12; ++j)
                    accZ = __builtin_amdgcn_mfma_f32_16x16x32_f16(xf[j], bx[j], accZ, 0, 0, 0);

                wait_slots(semh1, 128, (unsigned)(t + 1));        // all of h1(t)
                const half_t* hb = h1_t + (size_t)zarow * DH + l4 * 8;
                half8 hf[16], bh[16];
                ldA8(hb,       hf[0], hf[1], hf[2], hf[3], hf[4], hf[5], hf[6], hf[7]);
                ldA8(hb + 256, hf[8], hf[9], hf[10], hf[11], hf[12], hf[13], hf[14], hf[15]);
                ldC8(wb + 384,       bh[0], bh[1], bh[2], bh[3], bh[4], bh[5], bh[6], bh[7]);
                ldC8(wb + 384 + 256, bh[8], bh[9], bh[10], bh[11], bh[12], bh[13], bh[14], bh[15]);
                WAITVM(0);
                #pragma unroll
                for (int j = 0; j < 16; ++j)
                    accZ = __builtin_amdgcn_mfma_f32_16x16x32_f16(hf[j], bh[j], accZ, 0, 0, 0);
                const float bb = b1f[zn];
                float zv[4];
                #pragma unroll
                for (int r = 0; r < 4; ++r) zv[r] = fmaxf(accZ[r] + bb, 0.f);
                bounce_out(zv, z_n + (size_t)(zr * 64) * DH + zc * 16);
                signal_slot(semz, lwg, (unsigned)(t + 2));
            }
        }
    }
}

// ---------------------------------------------------------------------------

extern "C" void kernel_launch(void* const* d_in, const int* in_sizes, int n_in,
                              void* d_out, int out_size, void* d_ws, size_t ws_size,
                              hipStream_t stream) {
    const float* x    = (const float*)d_in[0];
    const float* w1   = (const float*)d_in[1];
    const float* b1   = (const float*)d_in[2];
    const float* w_ih = (const float*)d_in[3];
    const float* w_hh = (const float*)d_in[4];
    const float* b_ih = (const float*)d_in[5];
    const float* b_hh = (const float*)d_in[6];
    const float* w2   = (const float*)d_in[7];
    const float* b2   = (const float*)d_in[8];
    float* out = (float*)d_out;
    (void)in_sizes; (void)n_in; (void)out_size; (void)ws_size;

    char* ws = (char*)d_ws;
    size_t off = 0;
    auto take = [&](size_t bytes) -> char* {
        char* p = ws + off;
        off += (bytes + 255) & ~(size_t)255;
        return p;
    };
    half_t* W1h  = (half_t*)take((size_t)512 * 512 * 2);
    half_t* W2h  = (half_t*)take((size_t)128 * 512 * 2);
    half_t* W1f  = (half_t*)take((size_t)512 * KZ * 2);
    half_t* Wl0p = (half_t*)take((size_t)NG * 1024 * 2);   // [ih 2MB | hh 2MB]
    half_t* Wl1p = (half_t*)take((size_t)NG * 1024 * 2);
    float*  b1f  = (float*)take((size_t)512 * 4);
    float*  bP0  = (float*)take((size_t)NG * 4);
    float*  bP1  = (float*)take((size_t)NG * 4);
    half_t* zbuf  = (half_t*)take((size_t)2 * NB * DH * 2);
    half_t* h0buf = (half_t*)take((size_t)2 * NB * DH * 2);
    half_t* h1buf = (half_t*)take((size_t)2 * NB * DH * 2);
    half_t* xhst  = (half_t*)take((size_t)2 * NB * DIN * 2);
    unsigned* semz  = (unsigned*)take((size_t)128 * 16 * 4);
    unsigned* semh0 = (unsigned*)take((size_t)128 * 16 * 4);
    unsigned* semh1 = (unsigned*)take((size_t)128 * 16 * 4);
    unsigned* semxh = (unsigned*)take((size_t)128 * 16 * 4);

    cvt_f32_f16<<<256, 256, 0, stream>>>(w1, W1h, 512 * 512);
    cvt_f32_f16<<<64, 256, 0, stream>>>(w2, W2h, 128 * 512);
    fold_w1<<<512, 256, 0, stream>>>(w1, w2, b1, b2, W1f, b1f);
    pack512<<<512, 256, 0, stream>>>(w_ih, Wl0p);
    pack512<<<512, 256, 0, stream>>>(w_hh, Wl0p + 1048576);
    pack512<<<512, 256, 0, stream>>>(w_ih + (size_t)NG * DH, Wl1p);
    pack512<<<512, 256, 0, stream>>>(w_hh + (size_t)NG * DH, Wl1p + 1048576);
    pack_bias<<<8, 256, 0, stream>>>(b_ih, b_hh, bP0);
    pack_bias<<<8, 256, 0, stream>>>(b_ih + NG, b_hh + NG, bP1);
    init_all<<<32, 256, 0, stream>>>(semz, 4 * 128 * 16);   // zeroes all 4 (contiguous)

    hipFuncSetAttribute((const void*)rnn_persistent,
                        hipFuncAttributeMaxDynamicSharedMemorySize, SMEM);

    void* args[] = { (void*)&x, (void*)&W1h, (void*)&W1f, (void*)&b1, (void*)&b1f,
                     (void*)&Wl0p, (void*)&bP0, (void*)&Wl1p, (void*)&bP1,
                     (void*)&W2h, (void*)&b2, (void*)&zbuf, (void*)&h0buf,
                     (void*)&h1buf, (void*)&xhst, (void*)&out,
                     (void*)&semz, (void*)&semh0, (void*)&semh1, (void*)&semxh };
    hipError_t e = hipLaunchCooperativeKernel((void*)rnn_persistent, dim3(NWG), dim3(256),
                                              args, SMEM, stream);
    if (e != hipSuccess) {
        rnn_persistent<<<dim3(NWG), dim3(256), SMEM, stream>>>(
            x, W1h, W1f, b1, b1f, Wl0p, bP0, Wl1p, bP1, W2h, b2,
            zbuf, h0buf, h1buf, xhst, out, semz, semh0, semh1, semxh);
    }
}